// Round 1
// baseline (1133.993 us; speedup 1.0000x reference)
//
#include <hip/hip_runtime.h>
#include <hip/hip_bf16.h>

// WindowAttention: B=128 windows, N=512 tokens, C=256, H=8 heads, D=32.
// Round 1: correctness-first full-fp32 pipeline.
//   ws layout:
//     qbuf  f32 (B,H,N,D)   67,108,864 B   (overwritten with attn output)
//     kbuf  bf16 (B,H,N,D)  33,554,432 B   (bf16 rounding of k is provably harmless)
//     vbuf  f32 (B,H,N,D)   67,108,864 B
//     bias  f32 (H,N,N)      8,388,608 B
//     tbl   f32 (3375,8)       108,000 B
//   total ~176.3 MB

#define ATTN_SCALE 0.17677669529663687f  // 1/sqrt(32)

// ---------------- kernel 1: CPB MLP -> 16*sigmoid table ----------------
__global__ __launch_bounds__(512) void cpb_kernel(
    const float* __restrict__ rpb, const float* __restrict__ w1,
    const float* __restrict__ b1, const float* __restrict__ w2,
    float* __restrict__ table16) {
  __shared__ float hid[512];
  const int p = blockIdx.x;   // 0..3374
  const int t = threadIdx.x;  // 0..511
  const float r0 = rpb[p * 3 + 0], r1 = rpb[p * 3 + 1], r2 = rpb[p * 3 + 2];
  float hv = fmaf(r0, w1[t * 3 + 0],
             fmaf(r1, w1[t * 3 + 1],
             fmaf(r2, w1[t * 3 + 2], b1[t])));
  hid[t] = fmaxf(hv, 0.0f);
  __syncthreads();
  const int h = t >> 6, lane = t & 63;  // 8 waves, one head per wave
  float s = 0.0f;
#pragma unroll
  for (int u = 0; u < 8; ++u)
    s = fmaf(hid[lane + u * 64], w2[h * 512 + lane + u * 64], s);
#pragma unroll
  for (int off = 32; off > 0; off >>= 1) s += __shfl_down(s, off);
  if (lane == 0) table16[p * 8 + h] = 16.0f / (1.0f + __expf(-s));
}

// ---------------- kernel 2: gather bias (H,N,N) ----------------
__global__ __launch_bounds__(256) void bias_kernel(
    const int* __restrict__ rpb_idx, const float* __restrict__ table16,
    float* __restrict__ bias) {
  const int ij = blockIdx.x * 256 + threadIdx.x;  // 0..262143
  const int idx = rpb_idx[ij];
#pragma unroll
  for (int h = 0; h < 8; ++h)
    bias[(size_t)h * 262144 + ij] = table16[idx * 8 + h];
}

// ---------------- kernel 3: qkv GEMM (M=65536,N=768,K=256) + scatter ----------------
__global__ __launch_bounds__(256) void qkv_gemm(
    const float* __restrict__ x, const float* __restrict__ w,
    float* __restrict__ qbuf, __hip_bfloat16* __restrict__ kbuf,
    float* __restrict__ vbuf) {
  __shared__ float As[16][128];
  __shared__ float Bs[16][128];
  const int tid = threadIdx.x;
  const int bn = blockIdx.x;  // 0..5
  const int bm = blockIdx.y;  // 0..511
  const int arow = tid >> 1;
  const int acol = (tid & 1) * 8;
  const float* aptr = x + (size_t)(bm * 128 + arow) * 256 + acol;
  const float* bptr = w + (size_t)(bn * 128 + arow) * 256 + acol;
  const int tx = tid & 15, ty = tid >> 4;
  float acc[8][8] = {};
  for (int k0 = 0; k0 < 256; k0 += 16) {
    float4 a0 = *reinterpret_cast<const float4*>(aptr + k0);
    float4 a1 = *reinterpret_cast<const float4*>(aptr + k0 + 4);
    float4 b0 = *reinterpret_cast<const float4*>(bptr + k0);
    float4 b1 = *reinterpret_cast<const float4*>(bptr + k0 + 4);
    __syncthreads();
    As[acol + 0][arow] = a0.x; As[acol + 1][arow] = a0.y;
    As[acol + 2][arow] = a0.z; As[acol + 3][arow] = a0.w;
    As[acol + 4][arow] = a1.x; As[acol + 5][arow] = a1.y;
    As[acol + 6][arow] = a1.z; As[acol + 7][arow] = a1.w;
    Bs[acol + 0][arow] = b0.x; Bs[acol + 1][arow] = b0.y;
    Bs[acol + 2][arow] = b0.z; Bs[acol + 3][arow] = b0.w;
    Bs[acol + 4][arow] = b1.x; Bs[acol + 5][arow] = b1.y;
    Bs[acol + 6][arow] = b1.z; Bs[acol + 7][arow] = b1.w;
    __syncthreads();
#pragma unroll
    for (int kk = 0; kk < 16; ++kk) {
      float a[8], b[8];
      *reinterpret_cast<float4*>(&a[0]) = *reinterpret_cast<const float4*>(&As[kk][ty * 8]);
      *reinterpret_cast<float4*>(&a[4]) = *reinterpret_cast<const float4*>(&As[kk][ty * 8 + 4]);
      *reinterpret_cast<float4*>(&b[0]) = *reinterpret_cast<const float4*>(&Bs[kk][tx * 8]);
      *reinterpret_cast<float4*>(&b[4]) = *reinterpret_cast<const float4*>(&Bs[kk][tx * 8 + 4]);
#pragma unroll
      for (int i = 0; i < 8; ++i)
#pragma unroll
        for (int j = 0; j < 8; ++j) acc[i][j] = fmaf(a[i], b[j], acc[i][j]);
    }
  }
  // epilogue: scatter into (b,h,n,d). sec uniform per block (BN=128 | 256 boundary)
  const int sec = (bn * 128) >> 8;  // 0=q,1=k,2=v
  const int m0 = bm * 128 + ty * 8;
  const int n0 = bn * 128 + tx * 8;
  const int h = (n0 & 255) >> 5;
  const int d = n0 & 31;  // in {0,8,16,24}; 8 consecutive d's stay in one head
#pragma unroll
  for (int i = 0; i < 8; ++i) {
    const int m = m0 + i;
    const int b = m >> 9;
    const int ii = m & 511;
    const size_t off = ((size_t)(b * 8 + h) * 512 + ii) * 32 + d;
    if (sec == 0) {
      *reinterpret_cast<float4*>(qbuf + off) =
          make_float4(acc[i][0], acc[i][1], acc[i][2], acc[i][3]);
      *reinterpret_cast<float4*>(qbuf + off + 4) =
          make_float4(acc[i][4], acc[i][5], acc[i][6], acc[i][7]);
    } else if (sec == 1) {
#pragma unroll
      for (int j = 0; j < 8; ++j) kbuf[off + j] = __float2bfloat16(acc[i][j]);
    } else {
      *reinterpret_cast<float4*>(vbuf + off) =
          make_float4(acc[i][0], acc[i][1], acc[i][2], acc[i][3]);
      *reinterpret_cast<float4*>(vbuf + off + 4) =
          make_float4(acc[i][4], acc[i][5], acc[i][6], acc[i][7]);
    }
  }
}

// ---------------- kernel 4: fused bias+mask attention (flash-style) ----------------
// grid (qc=2, h=8, b=128), 256 threads, thread-per-query-row.
// Reads q rows from qbuf, writes attention output back over the same rows.
__global__ __launch_bounds__(256) void attn_kernel(
    float* qbuf,  // aliased in/out - no restrict
    const __hip_bfloat16* __restrict__ kbuf, const float* __restrict__ vbuf,
    const float* __restrict__ biasbuf, const float* __restrict__ mask) {
  __shared__ float Ks[32][32];
  __shared__ float Vs[32][32];
  const int t = threadIdx.x;
  const int qc = blockIdx.x, h = blockIdx.y, b = blockIdx.z;
  const int i = qc * 256 + t;
  const size_t bh = (size_t)(b * 8 + h);
  float* qrow = qbuf + (bh * 512 + i) * 32;
  float q[32];
#pragma unroll
  for (int d4 = 0; d4 < 8; ++d4) {
    float4 qv = *reinterpret_cast<const float4*>(qrow + d4 * 4);
    q[d4 * 4 + 0] = qv.x * ATTN_SCALE;
    q[d4 * 4 + 1] = qv.y * ATTN_SCALE;
    q[d4 * 4 + 2] = qv.z * ATTN_SCALE;
    q[d4 * 4 + 3] = qv.w * ATTN_SCALE;
  }
  const __hip_bfloat16* kbase = kbuf + bh * 512 * 32;
  const float* vbase = vbuf + bh * 512 * 32;
  const float* biasrow = biasbuf + (size_t)h * 262144 + (size_t)i * 512;
  const float* maskrow = mask + (size_t)(b & 15) * 262144 + (size_t)i * 512;
  float acc[32] = {};
  float mrun = -3.0e38f, l = 0.0f;
  const int srow = t >> 3;          // 0..31
  const int scol = (t & 7) * 4;     // 0..28
  for (int j0 = 0; j0 < 512; j0 += 32) {
    // cooperative stage of K (bf16->f32) and V tiles
    const __hip_bfloat162* kp2 = reinterpret_cast<const __hip_bfloat162*>(
        kbase + (size_t)(j0 + srow) * 32 + scol);
    const __hip_bfloat162 ka = kp2[0], kb = kp2[1];
    const float4 vv = *reinterpret_cast<const float4*>(
        vbase + (size_t)(j0 + srow) * 32 + scol);
    const float2 f0 = __bfloat1622float2(ka), f1 = __bfloat1622float2(kb);
    __syncthreads();
    *reinterpret_cast<float4*>(&Ks[srow][scol]) = make_float4(f0.x, f0.y, f1.x, f1.y);
    *reinterpret_cast<float4*>(&Vs[srow][scol]) = vv;
    __syncthreads();
    float s[32];
#pragma unroll
    for (int u = 0; u < 8; ++u) {
      float4 bb = *reinterpret_cast<const float4*>(biasrow + j0 + u * 4);
      float4 mm = *reinterpret_cast<const float4*>(maskrow + j0 + u * 4);
      s[u * 4 + 0] = bb.x + mm.x;
      s[u * 4 + 1] = bb.y + mm.y;
      s[u * 4 + 2] = bb.z + mm.z;
      s[u * 4 + 3] = bb.w + mm.w;
    }
#pragma unroll
    for (int jj = 0; jj < 32; ++jj) {
      float sv = s[jj];
#pragma unroll
      for (int d4 = 0; d4 < 8; ++d4) {
        float4 kk = *reinterpret_cast<const float4*>(&Ks[jj][d4 * 4]);
        sv = fmaf(q[d4 * 4 + 0], kk.x, sv);
        sv = fmaf(q[d4 * 4 + 1], kk.y, sv);
        sv = fmaf(q[d4 * 4 + 2], kk.z, sv);
        sv = fmaf(q[d4 * 4 + 3], kk.w, sv);
      }
      s[jj] = sv;
    }
    float mnew = mrun;
#pragma unroll
    for (int jj = 0; jj < 32; ++jj) mnew = fmaxf(mnew, s[jj]);
    const float corr = __expf(mrun - mnew);
    mrun = mnew;
    l *= corr;
#pragma unroll
    for (int d = 0; d < 32; ++d) acc[d] *= corr;
#pragma unroll
    for (int jj = 0; jj < 32; ++jj) {
      const float p = __expf(s[jj] - mnew);
      l += p;
#pragma unroll
      for (int d4 = 0; d4 < 8; ++d4) {
        float4 vv2 = *reinterpret_cast<const float4*>(&Vs[jj][d4 * 4]);
        acc[d4 * 4 + 0] = fmaf(p, vv2.x, acc[d4 * 4 + 0]);
        acc[d4 * 4 + 1] = fmaf(p, vv2.y, acc[d4 * 4 + 1]);
        acc[d4 * 4 + 2] = fmaf(p, vv2.z, acc[d4 * 4 + 2]);
        acc[d4 * 4 + 3] = fmaf(p, vv2.w, acc[d4 * 4 + 3]);
      }
    }
  }
  const float inv = 1.0f / l;
#pragma unroll
  for (int d4 = 0; d4 < 8; ++d4) {
    float4 o4 = make_float4(acc[d4 * 4 + 0] * inv, acc[d4 * 4 + 1] * inv,
                            acc[d4 * 4 + 2] * inv, acc[d4 * 4 + 3] * inv);
    *reinterpret_cast<float4*>(qrow + d4 * 4) = o4;
  }
}

// ---------------- kernel 5: proj GEMM (M=65536,N=256,K=256) + bias ----------------
__global__ __launch_bounds__(256) void proj_gemm(
    const float* __restrict__ abuf,  // attn output in (b,h,n,d) layout (= qbuf)
    const float* __restrict__ w, const float* __restrict__ pb,
    float* __restrict__ out) {
  __shared__ float As[16][128];
  __shared__ float Bs[16][128];
  const int tid = threadIdx.x;
  const int bn = blockIdx.x;  // 0..1
  const int bm = blockIdx.y;  // 0..511
  const int arow = tid >> 1;
  const int acol = (tid & 1) * 8;
  const int m = bm * 128 + arow;
  const int bb_ = m >> 9;
  const int ii = m & 511;
  const float* base_bi = abuf + ((size_t)bb_ * 8 * 512 + ii) * 32;
  const float* bptr = w + (size_t)(bn * 128 + arow) * 256 + acol;
  const int tx = tid & 15, ty = tid >> 4;
  float acc[8][8] = {};
  for (int k0 = 0; k0 < 256; k0 += 16) {
    const int c0 = k0 + acol;
    const int hh = c0 >> 5;
    const int dd = c0 & 31;
    const float* ap = base_bi + (size_t)hh * 512 * 32 + dd;
    float4 a0 = *reinterpret_cast<const float4*>(ap);
    float4 a1 = *reinterpret_cast<const float4*>(ap + 4);
    float4 b0 = *reinterpret_cast<const float4*>(bptr + k0);
    float4 b1 = *reinterpret_cast<const float4*>(bptr + k0 + 4);
    __syncthreads();
    As[acol + 0][arow] = a0.x; As[acol + 1][arow] = a0.y;
    As[acol + 2][arow] = a0.z; As[acol + 3][arow] = a0.w;
    As[acol + 4][arow] = a1.x; As[acol + 5][arow] = a1.y;
    As[acol + 6][arow] = a1.z; As[acol + 7][arow] = a1.w;
    Bs[acol + 0][arow] = b0.x; Bs[acol + 1][arow] = b0.y;
    Bs[acol + 2][arow] = b0.z; Bs[acol + 3][arow] = b0.w;
    Bs[acol + 4][arow] = b1.x; Bs[acol + 5][arow] = b1.y;
    Bs[acol + 6][arow] = b1.z; Bs[acol + 7][arow] = b1.w;
    __syncthreads();
#pragma unroll
    for (int kk = 0; kk < 16; ++kk) {
      float a[8], b[8];
      *reinterpret_cast<float4*>(&a[0]) = *reinterpret_cast<const float4*>(&As[kk][ty * 8]);
      *reinterpret_cast<float4*>(&a[4]) = *reinterpret_cast<const float4*>(&As[kk][ty * 8 + 4]);
      *reinterpret_cast<float4*>(&b[0]) = *reinterpret_cast<const float4*>(&Bs[kk][tx * 8]);
      *reinterpret_cast<float4*>(&b[4]) = *reinterpret_cast<const float4*>(&Bs[kk][tx * 8 + 4]);
#pragma unroll
      for (int i = 0; i < 8; ++i)
#pragma unroll
        for (int j = 0; j < 8; ++j) acc[i][j] = fmaf(a[i], b[j], acc[i][j]);
    }
  }
  const int m0 = bm * 128 + ty * 8;
  const int n0 = bn * 128 + tx * 8;
  const float4 pb0 = *reinterpret_cast<const float4*>(pb + n0);
  const float4 pb1 = *reinterpret_cast<const float4*>(pb + n0 + 4);
#pragma unroll
  for (int i = 0; i < 8; ++i) {
    const size_t off = (size_t)(m0 + i) * 256 + n0;
    *reinterpret_cast<float4*>(out + off) =
        make_float4(acc[i][0] + pb0.x, acc[i][1] + pb0.y,
                    acc[i][2] + pb0.z, acc[i][3] + pb0.w);
    *reinterpret_cast<float4*>(out + off + 4) =
        make_float4(acc[i][4] + pb1.x, acc[i][5] + pb1.y,
                    acc[i][6] + pb1.z, acc[i][7] + pb1.w);
  }
}

extern "C" void kernel_launch(void* const* d_in, const int* in_sizes, int n_in,
                              void* d_out, int out_size, void* d_ws, size_t ws_size,
                              hipStream_t stream) {
  const float* x = (const float*)d_in[0];
  const float* mask = (const float*)d_in[1];
  const float* qkv_w = (const float*)d_in[2];
  const float* proj_w = (const float*)d_in[3];
  const float* proj_b = (const float*)d_in[4];
  const float* cpb_w1 = (const float*)d_in[5];
  const float* cpb_b1 = (const float*)d_in[6];
  const float* cpb_w2 = (const float*)d_in[7];
  const float* rpb = (const float*)d_in[8];
  const int* rpb_idx = (const int*)d_in[9];
  float* out = (float*)d_out;

  char* ws = (char*)d_ws;
  float* qbuf = (float*)(ws);                                // 67,108,864 B
  __hip_bfloat16* kbuf = (__hip_bfloat16*)(ws + 67108864);   // 33,554,432 B
  float* vbuf = (float*)(ws + 100663296);                    // 67,108,864 B
  float* biasbuf = (float*)(ws + 167772160);                 //  8,388,608 B
  float* table16 = (float*)(ws + 176160768);                 //    108,000 B

  cpb_kernel<<<3375, 512, 0, stream>>>(rpb, cpb_w1, cpb_b1, cpb_w2, table16);
  bias_kernel<<<1024, 256, 0, stream>>>(rpb_idx, table16, biasbuf);
  qkv_gemm<<<dim3(6, 512), 256, 0, stream>>>(x, qkv_w, qbuf, kbuf, vbuf);
  attn_kernel<<<dim3(2, 8, 128), 256, 0, stream>>>(qbuf, kbuf, vbuf, biasbuf, mask);
  proj_gemm<<<dim3(2, 512), 256, 0, stream>>>(qbuf, proj_w, proj_b, out);
}

// Round 3
// 597.745 us; speedup vs baseline: 1.8971x; 1.8971x over previous
//
#include <hip/hip_runtime.h>
#include <hip/hip_bf16.h>

// WindowAttention: B=128 windows, N=512, C=256, H=8, D=32.
// Round 3: MFMA bf16 attention (swapped QK^T, x16 PV, no-max exp2 softmax).
// Fix vs R2: __exp2f -> __builtin_amdgcn_exp2f (v_exp_f32).
// ws layout (bytes):
//   qbuf  bf16 (B,H,N,D)  @ 0           33,554,432  (q pre-scaled by 1/sqrt(32)*log2e; overwritten by attn out)
//   kbuf  bf16 (B,H,N,D)  @ 33,554,432  33,554,432
//   vbuf  bf16 (B,H,N,D)  @ 67,108,864  33,554,432
//   cmb   bf16 (16,8,N,N) @ 100,663,296 67,108,864  (16*sigmoid*log2e + mask*log2e - 11.65, centered)
//   tbl   f32  (3375,8)   @ 167,772,160    108,000
// total ~167.9 MB

using u16 = unsigned short;
using u32 = unsigned int;
typedef short bf16x4 __attribute__((ext_vector_type(4)));
typedef short bf16x8 __attribute__((ext_vector_type(8)));
typedef float f32x4 __attribute__((ext_vector_type(4)));

#define QSL 0.25503471f       // (1/sqrt(32)) * log2(e)
#define LOG2E 1.44269504f
#define CMB_SHIFT 11.65f      // centers bias*log2e (~11.66); softmax shift-invariant

static __device__ __forceinline__ u32 cvt_pk_bf16(float lo, float hi) {
  u32 r;
  asm("v_cvt_pk_bf16_f32 %0, %1, %2" : "=v"(r) : "v"(lo), "v"(hi));
  return r;
}

// ---------------- kernel 1: CPB MLP -> 16*sigmoid*log2e table ----------------
__global__ __launch_bounds__(512) void cpb_kernel(
    const float* __restrict__ rpb, const float* __restrict__ w1,
    const float* __restrict__ b1, const float* __restrict__ w2,
    float* __restrict__ table16) {
  __shared__ float hid[512];
  const int p = blockIdx.x;   // 0..3374
  const int t = threadIdx.x;  // 0..511
  const float r0 = rpb[p * 3 + 0], r1 = rpb[p * 3 + 1], r2 = rpb[p * 3 + 2];
  float hv = fmaf(r0, w1[t * 3 + 0],
             fmaf(r1, w1[t * 3 + 1],
             fmaf(r2, w1[t * 3 + 2], b1[t])));
  hid[t] = fmaxf(hv, 0.0f);
  __syncthreads();
  const int h = t >> 6, lane = t & 63;  // 8 waves, one head per wave
  float s = 0.0f;
#pragma unroll
  for (int u = 0; u < 8; ++u)
    s = fmaf(hid[lane + u * 64], w2[h * 512 + lane + u * 64], s);
#pragma unroll
  for (int off = 32; off > 0; off >>= 1) s += __shfl_down(s, off);
  if (lane == 0) table16[p * 8 + h] = 23.08312065f / (1.0f + __expf(-s));  // 16*log2e*sigmoid
}

// ---------------- kernel 2: combined centered bias+mask (bf16) ----------------
__global__ __launch_bounds__(256) void cmb_kernel(
    const int* __restrict__ rpb_idx, const float* __restrict__ table16,
    const float* __restrict__ mask, u16* __restrict__ cmb) {
  const int ij = blockIdx.x * 256 + threadIdx.x;  // 0..262143
  const int wh = blockIdx.y;                      // w*8+h
  const int w = wh >> 3, hh = wh & 7;
  const float v = table16[rpb_idx[ij] * 8 + hh]
                + mask[(size_t)w * 262144 + ij] * LOG2E - CMB_SHIFT;
  cmb[(size_t)wh * 262144 + ij] = (u16)(cvt_pk_bf16(v, v) & 0xffffu);
}

// ---------------- kernel 3: qkv GEMM (fp32 compute) + bf16 scatter ----------------
__global__ __launch_bounds__(256) void qkv_gemm(
    const float* __restrict__ x, const float* __restrict__ w,
    u16* __restrict__ qbuf, u16* __restrict__ kbuf, u16* __restrict__ vbuf) {
  __shared__ float As[16][128];
  __shared__ float Bs[16][128];
  const int tid = threadIdx.x;
  const int bn = blockIdx.x;  // 0..5
  const int bm = blockIdx.y;  // 0..511
  const int arow = tid >> 1;
  const int acol = (tid & 1) * 8;
  const float* aptr = x + (size_t)(bm * 128 + arow) * 256 + acol;
  const float* bptr = w + (size_t)(bn * 128 + arow) * 256 + acol;
  const int tx = tid & 15, ty = tid >> 4;
  float acc[8][8] = {};
  for (int k0 = 0; k0 < 256; k0 += 16) {
    float4 a0 = *reinterpret_cast<const float4*>(aptr + k0);
    float4 a1 = *reinterpret_cast<const float4*>(aptr + k0 + 4);
    float4 b0 = *reinterpret_cast<const float4*>(bptr + k0);
    float4 b1 = *reinterpret_cast<const float4*>(bptr + k0 + 4);
    __syncthreads();
    As[acol + 0][arow] = a0.x; As[acol + 1][arow] = a0.y;
    As[acol + 2][arow] = a0.z; As[acol + 3][arow] = a0.w;
    As[acol + 4][arow] = a1.x; As[acol + 5][arow] = a1.y;
    As[acol + 6][arow] = a1.z; As[acol + 7][arow] = a1.w;
    Bs[acol + 0][arow] = b0.x; Bs[acol + 1][arow] = b0.y;
    Bs[acol + 2][arow] = b0.z; Bs[acol + 3][arow] = b0.w;
    Bs[acol + 4][arow] = b1.x; Bs[acol + 5][arow] = b1.y;
    Bs[acol + 6][arow] = b1.z; Bs[acol + 7][arow] = b1.w;
    __syncthreads();
#pragma unroll
    for (int kk = 0; kk < 16; ++kk) {
      float a[8], b[8];
      *reinterpret_cast<float4*>(&a[0]) = *reinterpret_cast<const float4*>(&As[kk][ty * 8]);
      *reinterpret_cast<float4*>(&a[4]) = *reinterpret_cast<const float4*>(&As[kk][ty * 8 + 4]);
      *reinterpret_cast<float4*>(&b[0]) = *reinterpret_cast<const float4*>(&Bs[kk][tx * 8]);
      *reinterpret_cast<float4*>(&b[4]) = *reinterpret_cast<const float4*>(&Bs[kk][tx * 8 + 4]);
#pragma unroll
      for (int i = 0; i < 8; ++i)
#pragma unroll
        for (int j = 0; j < 8; ++j) acc[i][j] = fmaf(a[i], b[j], acc[i][j]);
    }
  }
  // epilogue: bf16 scatter into (b,h,n,d). q pre-scaled by QSL.
  const int sec = (bn * 128) >> 8;  // 0=q,1=k,2=v (uniform per block)
  u16* dst = sec == 0 ? qbuf : (sec == 1 ? kbuf : vbuf);
  const float scl = sec == 0 ? QSL : 1.0f;
  const int m0 = bm * 128 + ty * 8;
  const int n0 = bn * 128 + tx * 8;
  const int h = (n0 & 255) >> 5;
  const int d = n0 & 31;
#pragma unroll
  for (int i = 0; i < 8; ++i) {
    const int m = m0 + i;
    const int bb = m >> 9;
    const int ii = m & 511;
    const size_t off = ((size_t)(bb * 8 + h) * 512 + ii) * 32 + d;
    uint4 w4;
    w4.x = cvt_pk_bf16(acc[i][0] * scl, acc[i][1] * scl);
    w4.y = cvt_pk_bf16(acc[i][2] * scl, acc[i][3] * scl);
    w4.z = cvt_pk_bf16(acc[i][4] * scl, acc[i][5] * scl);
    w4.w = cvt_pk_bf16(acc[i][6] * scl, acc[i][7] * scl);
    *reinterpret_cast<uint4*>(dst + off) = w4;
  }
}

// ---------------- kernel 4: MFMA attention ----------------
// grid (qc=2, h=8, bz=128), 256 threads = 4 waves, wave owns 64 q-rows.
// S^T = mfma_16x16x32(K, Q, cmb)  -> frag rows=keys(4g+r), cols=q(lane&15)
// p = exp2(S^T)  (scores bounded; softmax shift-invariant, no running max)
// O^T += mfma_16x16x16(V^T, P^T)  -> P^T frag IS the B operand (no lane moves)
__global__ __launch_bounds__(256, 2) void attn_mfma(
    u16* qbuf,  // in: scaled Q; out: attention output (own rows only)
    const u16* __restrict__ kbuf, const u16* __restrict__ vbuf,
    const u16* __restrict__ cmb) {
  __shared__ u16 Klds[512 * 32];   // row-major keys, XOR-swizzled 16B chunks
  __shared__ u16 Vtlds[32 * 512];  // V transposed [d][n], XOR-swizzled
  const int t = threadIdx.x;
  const int qc = blockIdx.x, h = blockIdx.y;
  const int bz = blockIdx.z;
  const int b = ((bz & 15) << 3) | (bz >> 4);  // co-schedule same (b&15) blocks
  const size_t bh = (size_t)b * 8 + h;
  const u16* kb = kbuf + bh * 16384;
  const u16* vb = vbuf + bh * 16384;

  // ---- stage K: chunk id cid -> row cid>>2, 16B chunk cid&3, swizzled
#pragma unroll
  for (int c = 0; c < 8; ++c) {
    const int cid = t + c * 256;
    const int key = cid >> 2, ch = cid & 3;
    const uint4 kd = *reinterpret_cast<const uint4*>(kb + cid * 8);
    const int idx = key * 32 + ((ch * 8) ^ (((key >> 1) & 3) << 3));
    *reinterpret_cast<uint4*>(&Klds[idx]) = kd;
  }
  // ---- stage V transposed: Vt[d][n ^ ((d&7)<<3)]
#pragma unroll
  for (int r = 0; r < 2; ++r) {
    const int n = t + r * 256;
    const uint4 v0 = *reinterpret_cast<const uint4*>(vb + n * 32);
    const uint4 v1 = *reinterpret_cast<const uint4*>(vb + n * 32 + 8);
    const uint4 v2 = *reinterpret_cast<const uint4*>(vb + n * 32 + 16);
    const uint4 v3 = *reinterpret_cast<const uint4*>(vb + n * 32 + 24);
    const u32 wv16[16] = {v0.x, v0.y, v0.z, v0.w, v1.x, v1.y, v1.z, v1.w,
                          v2.x, v2.y, v2.z, v2.w, v3.x, v3.y, v3.z, v3.w};
#pragma unroll
    for (int u = 0; u < 16; ++u) {
      const int d0 = 2 * u, d1 = 2 * u + 1;
      Vtlds[d0 * 512 + (n ^ ((d0 & 7) << 3))] = (u16)(wv16[u] & 0xffffu);
      Vtlds[d1 * 512 + (n ^ ((d1 & 7) << 3))] = (u16)(wv16[u] >> 16);
    }
  }
  __syncthreads();

  const int lane = t & 63;
  const int lq = lane & 15, g = lane >> 4;
  const int wv = t >> 6;
  const int q0 = qc * 256 + wv * 64;

  // Q B-frags: lane holds Q[q][8g..8g+7]
  bf16x8 Qf[4];
  u16* qrowbase = qbuf + bh * 16384;
#pragma unroll
  for (int qt = 0; qt < 4; ++qt)
    Qf[qt] = *reinterpret_cast<const bf16x8*>(qrowbase + (q0 + qt * 16 + lq) * 32 + g * 8);

  const u16* cmbp[4];
  const size_t whbase = (size_t)((b & 15) * 8 + h) * 262144;
#pragma unroll
  for (int qt = 0; qt < 4; ++qt)
    cmbp[qt] = cmb + whbase + (size_t)(q0 + qt * 16 + lq) * 512 + 4 * g;

  const f32x4 fzero = {0.f, 0.f, 0.f, 0.f};
  f32x4 o[2][4];
  f32x4 lsum4[4];
#pragma unroll
  for (int qt = 0; qt < 4; ++qt) {
    lsum4[qt] = fzero;
    o[0][qt] = fzero;
    o[1][qt] = fzero;
  }

  for (int j0 = 0; j0 < 512; j0 += 64) {
    // K A-frags: lane holds K[key=kt*16+lq][8g..8g+7]
    bf16x8 Ak[4];
#pragma unroll
    for (int kt = 0; kt < 4; ++kt) {
      const int key = j0 + kt * 16 + lq;
      const int idx = key * 32 + ((g * 8) ^ (((key >> 1) & 3) << 3));
      Ak[kt] = *reinterpret_cast<const bf16x8*>(&Klds[idx]);
    }
    // S^T = K*Q^T + cmb
    f32x4 s[4][4];
#pragma unroll
    for (int kt = 0; kt < 4; ++kt)
#pragma unroll
      for (int qt = 0; qt < 4; ++qt) {
        const uint2 cc = *reinterpret_cast<const uint2*>(cmbp[qt] + j0 + kt * 16);
        f32x4 ci;
        ci[0] = __uint_as_float((cc.x & 0xffffu) << 16);
        ci[1] = __uint_as_float(cc.x & 0xffff0000u);
        ci[2] = __uint_as_float((cc.y & 0xffffu) << 16);
        ci[3] = __uint_as_float(cc.y & 0xffff0000u);
        s[kt][qt] = __builtin_amdgcn_mfma_f32_16x16x32_bf16(Ak[kt], Qf[qt], ci, 0, 0, 0);
      }
    // exp2, l-accumulate, pack to bf16, PV
#pragma unroll
    for (int kt = 0; kt < 4; ++kt) {
      bf16x4 Av[2];
#pragma unroll
      for (int dt = 0; dt < 2; ++dt) {
        const int d = dt * 16 + lq;
        const int n0 = j0 + kt * 16 + 4 * g;
        const int idx = d * 512 + (n0 ^ ((d & 7) << 3));
        Av[dt] = *reinterpret_cast<const bf16x4*>(&Vtlds[idx]);
      }
#pragma unroll
      for (int qt = 0; qt < 4; ++qt) {
        f32x4 p = s[kt][qt];
        p[0] = __builtin_amdgcn_exp2f(p[0]);
        p[1] = __builtin_amdgcn_exp2f(p[1]);
        p[2] = __builtin_amdgcn_exp2f(p[2]);
        p[3] = __builtin_amdgcn_exp2f(p[3]);
        lsum4[qt] += p;
        union { u32 u[2]; bf16x4 v; } bp;
        bp.u[0] = cvt_pk_bf16(p[0], p[1]);
        bp.u[1] = cvt_pk_bf16(p[2], p[3]);
        o[0][qt] = __builtin_amdgcn_mfma_f32_16x16x16bf16_1k(Av[0], bp.v, o[0][qt], 0, 0, 0);
        o[1][qt] = __builtin_amdgcn_mfma_f32_16x16x16bf16_1k(Av[1], bp.v, o[1][qt], 0, 0, 0);
      }
    }
  }
  // epilogue: l reduce across 4 lane-groups, write O = O^T/l into qbuf rows
#pragma unroll
  for (int qt = 0; qt < 4; ++qt) {
    float l = (lsum4[qt][0] + lsum4[qt][1]) + (lsum4[qt][2] + lsum4[qt][3]);
    l += __shfl_xor(l, 16);
    l += __shfl_xor(l, 32);
    const float inv = 1.0f / l;
    u16* orow = qrowbase + (q0 + qt * 16 + lq) * 32;
#pragma unroll
    for (int dt = 0; dt < 2; ++dt) {
      uint2 w2;
      w2.x = cvt_pk_bf16(o[dt][qt][0] * inv, o[dt][qt][1] * inv);
      w2.y = cvt_pk_bf16(o[dt][qt][2] * inv, o[dt][qt][3] * inv);
      *reinterpret_cast<uint2*>(orow + dt * 16 + 4 * g) = w2;
    }
  }
}

// ---------------- kernel 5: proj GEMM (fp32 compute, bf16 A) + bias ----------------
__global__ __launch_bounds__(256) void proj_gemm(
    const u16* __restrict__ abuf,  // attn output bf16 in (b,h,n,d) layout (= qbuf)
    const float* __restrict__ w, const float* __restrict__ pb,
    float* __restrict__ out) {
  __shared__ float As[16][128];
  __shared__ float Bs[16][128];
  const int tid = threadIdx.x;
  const int bn = blockIdx.x;  // 0..1
  const int bm = blockIdx.y;  // 0..511
  const int arow = tid >> 1;
  const int acol = (tid & 1) * 8;
  const int m = bm * 128 + arow;
  const int bb_ = m >> 9;
  const int ii = m & 511;
  const u16* base_bi = abuf + ((size_t)bb_ * 8 * 512 + ii) * 32;
  const float* bptr = w + (size_t)(bn * 128 + arow) * 256 + acol;
  const int tx = tid & 15, ty = tid >> 4;
  float acc[8][8] = {};
  for (int k0 = 0; k0 < 256; k0 += 16) {
    const int c0 = k0 + acol;
    const int hh = c0 >> 5;
    const int dd = c0 & 31;
    const u16* ap = base_bi + (size_t)hh * 16384 + dd;
    const uint4 ua = *reinterpret_cast<const uint4*>(ap);
    float4 b0 = *reinterpret_cast<const float4*>(bptr + k0);
    float4 b1 = *reinterpret_cast<const float4*>(bptr + k0 + 4);
    __syncthreads();
    As[acol + 0][arow] = __uint_as_float((ua.x & 0xffffu) << 16);
    As[acol + 1][arow] = __uint_as_float(ua.x & 0xffff0000u);
    As[acol + 2][arow] = __uint_as_float((ua.y & 0xffffu) << 16);
    As[acol + 3][arow] = __uint_as_float(ua.y & 0xffff0000u);
    As[acol + 4][arow] = __uint_as_float((ua.z & 0xffffu) << 16);
    As[acol + 5][arow] = __uint_as_float(ua.z & 0xffff0000u);
    As[acol + 6][arow] = __uint_as_float((ua.w & 0xffffu) << 16);
    As[acol + 7][arow] = __uint_as_float(ua.w & 0xffff0000u);
    Bs[acol + 0][arow] = b0.x; Bs[acol + 1][arow] = b0.y;
    Bs[acol + 2][arow] = b0.z; Bs[acol + 3][arow] = b0.w;
    Bs[acol + 4][arow] = b1.x; Bs[acol + 5][arow] = b1.y;
    Bs[acol + 6][arow] = b1.z; Bs[acol + 7][arow] = b1.w;
    __syncthreads();
#pragma unroll
    for (int kk = 0; kk < 16; ++kk) {
      float a[8], b[8];
      *reinterpret_cast<float4*>(&a[0]) = *reinterpret_cast<const float4*>(&As[kk][ty * 8]);
      *reinterpret_cast<float4*>(&a[4]) = *reinterpret_cast<const float4*>(&As[kk][ty * 8 + 4]);
      *reinterpret_cast<float4*>(&b[0]) = *reinterpret_cast<const float4*>(&Bs[kk][tx * 8]);
      *reinterpret_cast<float4*>(&b[4]) = *reinterpret_cast<const float4*>(&Bs[kk][tx * 8 + 4]);
#pragma unroll
      for (int i = 0; i < 8; ++i)
#pragma unroll
        for (int j = 0; j < 8; ++j) acc[i][j] = fmaf(a[i], b[j], acc[i][j]);
    }
  }
  const int m0 = bm * 128 + ty * 8;
  const int n0 = bn * 128 + tx * 8;
  const float4 pb0 = *reinterpret_cast<const float4*>(pb + n0);
  const float4 pb1 = *reinterpret_cast<const float4*>(pb + n0 + 4);
#pragma unroll
  for (int i = 0; i < 8; ++i) {
    const size_t off = (size_t)(m0 + i) * 256 + n0;
    *reinterpret_cast<float4*>(out + off) =
        make_float4(acc[i][0] + pb0.x, acc[i][1] + pb0.y,
                    acc[i][2] + pb0.z, acc[i][3] + pb0.w);
    *reinterpret_cast<float4*>(out + off + 4) =
        make_float4(acc[i][4] + pb1.x, acc[i][5] + pb1.y,
                    acc[i][6] + pb1.z, acc[i][7] + pb1.w);
  }
}

extern "C" void kernel_launch(void* const* d_in, const int* in_sizes, int n_in,
                              void* d_out, int out_size, void* d_ws, size_t ws_size,
                              hipStream_t stream) {
  const float* x = (const float*)d_in[0];
  const float* mask = (const float*)d_in[1];
  const float* qkv_w = (const float*)d_in[2];
  const float* proj_w = (const float*)d_in[3];
  const float* proj_b = (const float*)d_in[4];
  const float* cpb_w1 = (const float*)d_in[5];
  const float* cpb_b1 = (const float*)d_in[6];
  const float* cpb_w2 = (const float*)d_in[7];
  const float* rpb = (const float*)d_in[8];
  const int* rpb_idx = (const int*)d_in[9];
  float* out = (float*)d_out;

  char* ws = (char*)d_ws;
  u16* qbuf = (u16*)(ws);                       // 33,554,432 B
  u16* kbuf = (u16*)(ws + 33554432);            // 33,554,432 B
  u16* vbuf = (u16*)(ws + 67108864);            // 33,554,432 B
  u16* cmb = (u16*)(ws + 100663296);            // 67,108,864 B
  float* table16 = (float*)(ws + 167772160);    //    108,000 B

  cpb_kernel<<<3375, 512, 0, stream>>>(rpb, cpb_w1, cpb_b1, cpb_w2, table16);
  cmb_kernel<<<dim3(1024, 128), 256, 0, stream>>>(rpb_idx, table16, mask, cmb);
  qkv_gemm<<<dim3(6, 512), 256, 0, stream>>>(x, qkv_w, qbuf, kbuf, vbuf);
  attn_mfma<<<dim3(2, 8, 128), 256, 0, stream>>>(qbuf, kbuf, vbuf, cmb);
  proj_gemm<<<dim3(2, 512), 256, 0, stream>>>(qbuf, proj_w, proj_b, out);
}

// Round 6
// 320.824 us; speedup vs baseline: 3.5346x; 1.8632x over previous
//
#include <hip/hip_runtime.h>
#include <hip/hip_bf16.h>

// WindowAttention: B=128 windows, N=512, C=256, H=8, D=32.
// Round 6: fix R5's half-staged LDS tiles (stage all 128 rows: 4 rows/thread).
// bf16-MFMA qkv & proj GEMMs (128x128 tile, BK=64, XOR-swizzled LDS,
// f32->bf16 cast fused into staging). Attention kernel unchanged from R3.
// ws layout (bytes):
//   qbuf  bf16 (B,H,N,D)  @ 0           33,554,432  (q pre-scaled by 1/sqrt(32)*log2e; overwritten by attn out)
//   kbuf  bf16 (B,H,N,D)  @ 33,554,432  33,554,432
//   vbuf  bf16 (B,H,N,D)  @ 67,108,864  33,554,432
//   cmb   bf16 (16,8,N,N) @ 100,663,296 67,108,864  (16*sigmoid*log2e + mask*log2e - 11.65, centered)
//   tbl   f32  (3375,8)   @ 167,772,160    108,000
// total ~167.9 MB

using u16 = unsigned short;
using u32 = unsigned int;
typedef short bf16x4 __attribute__((ext_vector_type(4)));
typedef short bf16x8 __attribute__((ext_vector_type(8)));
typedef float f32x4 __attribute__((ext_vector_type(4)));

#define QSL 0.25503471f       // (1/sqrt(32)) * log2(e)
#define LOG2E 1.44269504f
#define CMB_SHIFT 11.65f      // centers bias*log2e (~11.66); softmax shift-invariant

static __device__ __forceinline__ u32 cvt_pk_bf16(float lo, float hi) {
  u32 r;
  asm("v_cvt_pk_bf16_f32 %0, %1, %2" : "=v"(r) : "v"(lo), "v"(hi));
  return r;
}

// ---------------- kernel 1: CPB MLP -> 16*sigmoid*log2e table ----------------
__global__ __launch_bounds__(512) void cpb_kernel(
    const float* __restrict__ rpb, const float* __restrict__ w1,
    const float* __restrict__ b1, const float* __restrict__ w2,
    float* __restrict__ table16) {
  __shared__ float hid[512];
  const int p = blockIdx.x;   // 0..3374
  const int t = threadIdx.x;  // 0..511
  const float r0 = rpb[p * 3 + 0], r1 = rpb[p * 3 + 1], r2 = rpb[p * 3 + 2];
  float hv = fmaf(r0, w1[t * 3 + 0],
             fmaf(r1, w1[t * 3 + 1],
             fmaf(r2, w1[t * 3 + 2], b1[t])));
  hid[t] = fmaxf(hv, 0.0f);
  __syncthreads();
  const int h = t >> 6, lane = t & 63;  // 8 waves, one head per wave
  float s = 0.0f;
#pragma unroll
  for (int u = 0; u < 8; ++u)
    s = fmaf(hid[lane + u * 64], w2[h * 512 + lane + u * 64], s);
#pragma unroll
  for (int off = 32; off > 0; off >>= 1) s += __shfl_down(s, off);
  if (lane == 0) table16[p * 8 + h] = 23.08312065f / (1.0f + __expf(-s));  // 16*log2e*sigmoid
}

// ---------------- kernel 2: combined centered bias+mask (bf16) ----------------
__global__ __launch_bounds__(256) void cmb_kernel(
    const int* __restrict__ rpb_idx, const float* __restrict__ table16,
    const float* __restrict__ mask, u16* __restrict__ cmb) {
  const int ij = blockIdx.x * 256 + threadIdx.x;  // 0..262143
  const int wh = blockIdx.y;                      // w*8+h
  const int w = wh >> 3, hh = wh & 7;
  const float v = table16[rpb_idx[ij] * 8 + hh]
                + mask[(size_t)w * 262144 + ij] * LOG2E - CMB_SHIFT;
  cmb[(size_t)wh * 262144 + ij] = (u16)(cvt_pk_bf16(v, v) & 0xffffu);
}

// ---------------- kernel 3: qkv GEMM, bf16 MFMA ----------------
// out[m][n] = sum_k x[m][k]*w[n][k], M=65536, N=768, K=256.
// 128x128 tile, BK=64, 4 waves 2x2 (wave tile 64x64), 16x16x32 MFMA.
// LDS tiles stored as [row][chunk16B ^ (row&7)]; each thread stages chunk
// (tid&7) of rows (tid>>3)+{0,32,64,96} -> full 128x8-chunk coverage.
__global__ __launch_bounds__(256) void qkv_mfma(
    const float* __restrict__ x, const float* __restrict__ w,
    u16* __restrict__ qbuf, u16* __restrict__ kbuf, u16* __restrict__ vbuf) {
  __shared__ u16 As[128 * 64];
  __shared__ u16 Bs[128 * 64];
  const int tid = threadIdx.x;
  const int bn = blockIdx.x;  // 0..5
  const int bm = blockIdx.y;  // 0..511
  const int m0 = bm * 128, n0 = bn * 128;
  const float scl = (bn < 2) ? QSL : 1.0f;
  const int lane = tid & 63, wid = tid >> 6;
  const int wm = wid >> 1, wn = wid & 1;
  const int lq = lane & 15, g = lane >> 4;
  const f32x4 fz = {0.f, 0.f, 0.f, 0.f};
  f32x4 acc[4][4];
#pragma unroll
  for (int i = 0; i < 4; ++i)
#pragma unroll
    for (int j = 0; j < 4; ++j) acc[i][j] = fz;

  const int r0 = tid >> 3;                      // 0..31
  const int ch = tid & 7;                       // 16B chunk within row
  const int sx = (ch ^ (r0 & 7)) << 3;          // swizzled u16 offset (const: rr*32 keeps row&7)

  for (int k0 = 0; k0 < 256; k0 += 64) {
    float4 ga[4][2], gb[4][2];
#pragma unroll
    for (int rr = 0; rr < 4; ++rr) {
      const int r = r0 + rr * 32;
      const float* ax = x + (size_t)(m0 + r) * 256 + k0 + ch * 8;
      ga[rr][0] = *reinterpret_cast<const float4*>(ax);
      ga[rr][1] = *reinterpret_cast<const float4*>(ax + 4);
      const float* bx = w + (size_t)(n0 + r) * 256 + k0 + ch * 8;
      gb[rr][0] = *reinterpret_cast<const float4*>(bx);
      gb[rr][1] = *reinterpret_cast<const float4*>(bx + 4);
    }
    __syncthreads();  // prior-iter LDS reads done
#pragma unroll
    for (int rr = 0; rr < 4; ++rr) {
      const int r = r0 + rr * 32;
      uint4 pk;
      pk.x = cvt_pk_bf16(ga[rr][0].x, ga[rr][0].y);
      pk.y = cvt_pk_bf16(ga[rr][0].z, ga[rr][0].w);
      pk.z = cvt_pk_bf16(ga[rr][1].x, ga[rr][1].y);
      pk.w = cvt_pk_bf16(ga[rr][1].z, ga[rr][1].w);
      *reinterpret_cast<uint4*>(&As[r * 64 + sx]) = pk;
      pk.x = cvt_pk_bf16(gb[rr][0].x * scl, gb[rr][0].y * scl);
      pk.y = cvt_pk_bf16(gb[rr][0].z * scl, gb[rr][0].w * scl);
      pk.z = cvt_pk_bf16(gb[rr][1].x * scl, gb[rr][1].y * scl);
      pk.w = cvt_pk_bf16(gb[rr][1].z * scl, gb[rr][1].w * scl);
      *reinterpret_cast<uint4*>(&Bs[r * 64 + sx]) = pk;
    }
    __syncthreads();
#pragma unroll
    for (int ks = 0; ks < 2; ++ks) {
      bf16x8 xf[4], wf[4];
#pragma unroll
      for (int mt = 0; mt < 4; ++mt) {
        const int row = wm * 64 + mt * 16 + lq;
        xf[mt] = *reinterpret_cast<const bf16x8*>(
            &As[row * 64 + (((ks * 4 + g) ^ (row & 7)) << 3)]);
      }
#pragma unroll
      for (int nt = 0; nt < 4; ++nt) {
        const int row = wn * 64 + nt * 16 + lq;
        wf[nt] = *reinterpret_cast<const bf16x8*>(
            &Bs[row * 64 + (((ks * 4 + g) ^ (row & 7)) << 3)]);
      }
#pragma unroll
      for (int mt = 0; mt < 4; ++mt)
#pragma unroll
        for (int nt = 0; nt < 4; ++nt)
          acc[mt][nt] = __builtin_amdgcn_mfma_f32_16x16x32_bf16(
              wf[nt], xf[mt], acc[mt][nt], 0, 0, 0);
    }
  }
  // epilogue: lane holds out[m][n=..+4g+r] (acc[mt][nt][r]), scatter bf16 to (b,h,i,d)
  const int sec = bn >> 1;  // 0=q,1=k,2=v (uniform per block)
  u16* dst = sec == 0 ? qbuf : (sec == 1 ? kbuf : vbuf);
#pragma unroll
  for (int mt = 0; mt < 4; ++mt) {
    const int m = m0 + wm * 64 + mt * 16 + lq;
    const int b = m >> 9, ii = m & 511;
#pragma unroll
    for (int nt = 0; nt < 4; ++nt) {
      const int n = n0 + wn * 64 + nt * 16 + 4 * g;
      const int h = (n & 255) >> 5;
      const int d = n & 31;
      const size_t off = ((size_t)(b * 8 + h) * 512 + ii) * 32 + d;
      uint2 o2;
      o2.x = cvt_pk_bf16(acc[mt][nt][0], acc[mt][nt][1]);
      o2.y = cvt_pk_bf16(acc[mt][nt][2], acc[mt][nt][3]);
      *reinterpret_cast<uint2*>(dst + off) = o2;
    }
  }
}

// ---------------- kernel 4: MFMA attention (unchanged from R3) ----------------
__global__ __launch_bounds__(256, 2) void attn_mfma(
    u16* qbuf,  // in: scaled Q; out: attention output (own rows only)
    const u16* __restrict__ kbuf, const u16* __restrict__ vbuf,
    const u16* __restrict__ cmb) {
  __shared__ u16 Klds[512 * 32];   // row-major keys, XOR-swizzled 16B chunks
  __shared__ u16 Vtlds[32 * 512];  // V transposed [d][n], XOR-swizzled
  const int t = threadIdx.x;
  const int qc = blockIdx.x, h = blockIdx.y;
  const int bz = blockIdx.z;
  const int b = ((bz & 15) << 3) | (bz >> 4);  // co-schedule same (b&15) blocks
  const size_t bh = (size_t)b * 8 + h;
  const u16* kb = kbuf + bh * 16384;
  const u16* vb = vbuf + bh * 16384;

#pragma unroll
  for (int c = 0; c < 8; ++c) {
    const int cid = t + c * 256;
    const int key = cid >> 2, ch = cid & 3;
    const uint4 kd = *reinterpret_cast<const uint4*>(kb + cid * 8);
    const int idx = key * 32 + ((ch * 8) ^ (((key >> 1) & 3) << 3));
    *reinterpret_cast<uint4*>(&Klds[idx]) = kd;
  }
#pragma unroll
  for (int r = 0; r < 2; ++r) {
    const int n = t + r * 256;
    const uint4 v0 = *reinterpret_cast<const uint4*>(vb + n * 32);
    const uint4 v1 = *reinterpret_cast<const uint4*>(vb + n * 32 + 8);
    const uint4 v2 = *reinterpret_cast<const uint4*>(vb + n * 32 + 16);
    const uint4 v3 = *reinterpret_cast<const uint4*>(vb + n * 32 + 24);
    const u32 wv16[16] = {v0.x, v0.y, v0.z, v0.w, v1.x, v1.y, v1.z, v1.w,
                          v2.x, v2.y, v2.z, v2.w, v3.x, v3.y, v3.z, v3.w};
#pragma unroll
    for (int u = 0; u < 16; ++u) {
      const int d0 = 2 * u, d1 = 2 * u + 1;
      Vtlds[d0 * 512 + (n ^ ((d0 & 7) << 3))] = (u16)(wv16[u] & 0xffffu);
      Vtlds[d1 * 512 + (n ^ ((d1 & 7) << 3))] = (u16)(wv16[u] >> 16);
    }
  }
  __syncthreads();

  const int lane = t & 63;
  const int lq = lane & 15, g = lane >> 4;
  const int wv = t >> 6;
  const int q0 = qc * 256 + wv * 64;

  bf16x8 Qf[4];
  u16* qrowbase = qbuf + bh * 16384;
#pragma unroll
  for (int qt = 0; qt < 4; ++qt)
    Qf[qt] = *reinterpret_cast<const bf16x8*>(qrowbase + (q0 + qt * 16 + lq) * 32 + g * 8);

  const u16* cmbp[4];
  const size_t whbase = (size_t)((b & 15) * 8 + h) * 262144;
#pragma unroll
  for (int qt = 0; qt < 4; ++qt)
    cmbp[qt] = cmb + whbase + (size_t)(q0 + qt * 16 + lq) * 512 + 4 * g;

  const f32x4 fzero = {0.f, 0.f, 0.f, 0.f};
  f32x4 o[2][4];
  f32x4 lsum4[4];
#pragma unroll
  for (int qt = 0; qt < 4; ++qt) {
    lsum4[qt] = fzero;
    o[0][qt] = fzero;
    o[1][qt] = fzero;
  }

  for (int j0 = 0; j0 < 512; j0 += 64) {
    bf16x8 Ak[4];
#pragma unroll
    for (int kt = 0; kt < 4; ++kt) {
      const int key = j0 + kt * 16 + lq;
      const int idx = key * 32 + ((g * 8) ^ (((key >> 1) & 3) << 3));
      Ak[kt] = *reinterpret_cast<const bf16x8*>(&Klds[idx]);
    }
    f32x4 s[4][4];
#pragma unroll
    for (int kt = 0; kt < 4; ++kt)
#pragma unroll
      for (int qt = 0; qt < 4; ++qt) {
        const uint2 cc = *reinterpret_cast<const uint2*>(cmbp[qt] + j0 + kt * 16);
        f32x4 ci;
        ci[0] = __uint_as_float((cc.x & 0xffffu) << 16);
        ci[1] = __uint_as_float(cc.x & 0xffff0000u);
        ci[2] = __uint_as_float((cc.y & 0xffffu) << 16);
        ci[3] = __uint_as_float(cc.y & 0xffff0000u);
        s[kt][qt] = __builtin_amdgcn_mfma_f32_16x16x32_bf16(Ak[kt], Qf[qt], ci, 0, 0, 0);
      }
#pragma unroll
    for (int kt = 0; kt < 4; ++kt) {
      bf16x4 Av[2];
#pragma unroll
      for (int dt = 0; dt < 2; ++dt) {
        const int d = dt * 16 + lq;
        const int n0 = j0 + kt * 16 + 4 * g;
        const int idx = d * 512 + (n0 ^ ((d & 7) << 3));
        Av[dt] = *reinterpret_cast<const bf16x4*>(&Vtlds[idx]);
      }
#pragma unroll
      for (int qt = 0; qt < 4; ++qt) {
        f32x4 p = s[kt][qt];
        p[0] = __builtin_amdgcn_exp2f(p[0]);
        p[1] = __builtin_amdgcn_exp2f(p[1]);
        p[2] = __builtin_amdgcn_exp2f(p[2]);
        p[3] = __builtin_amdgcn_exp2f(p[3]);
        lsum4[qt] += p;
        union { u32 u[2]; bf16x4 v; } bp;
        bp.u[0] = cvt_pk_bf16(p[0], p[1]);
        bp.u[1] = cvt_pk_bf16(p[2], p[3]);
        o[0][qt] = __builtin_amdgcn_mfma_f32_16x16x16bf16_1k(Av[0], bp.v, o[0][qt], 0, 0, 0);
        o[1][qt] = __builtin_amdgcn_mfma_f32_16x16x16bf16_1k(Av[1], bp.v, o[1][qt], 0, 0, 0);
      }
    }
  }
#pragma unroll
  for (int qt = 0; qt < 4; ++qt) {
    float l = (lsum4[qt][0] + lsum4[qt][1]) + (lsum4[qt][2] + lsum4[qt][3]);
    l += __shfl_xor(l, 16);
    l += __shfl_xor(l, 32);
    const float inv = 1.0f / l;
    u16* orow = qrowbase + (q0 + qt * 16 + lq) * 32;
#pragma unroll
    for (int dt = 0; dt < 2; ++dt) {
      uint2 w2;
      w2.x = cvt_pk_bf16(o[dt][qt][0] * inv, o[dt][qt][1] * inv);
      w2.y = cvt_pk_bf16(o[dt][qt][2] * inv, o[dt][qt][3] * inv);
      *reinterpret_cast<uint2*>(orow + dt * 16 + 4 * g) = w2;
    }
  }
}

// ---------------- kernel 5: proj GEMM, bf16 MFMA ----------------
// out[m][n] = sum_c attnout[m][c]*proj_w[n][c] + pb[n], M=65536, N=256, K=256.
// A source is bf16 in scattered (b,h,i,d) layout (qbuf after attention).
__global__ __launch_bounds__(256) void proj_mfma(
    const u16* __restrict__ abuf, const float* __restrict__ w,
    const float* __restrict__ pb, float* __restrict__ out) {
  __shared__ u16 As[128 * 64];
  __shared__ u16 Bs[128 * 64];
  const int tid = threadIdx.x;
  const int bn = blockIdx.x;  // 0..1
  const int bm = blockIdx.y;  // 0..511
  const int m0 = bm * 128, n0 = bn * 128;
  const int lane = tid & 63, wid = tid >> 6;
  const int wm = wid >> 1, wn = wid & 1;
  const int lq = lane & 15, g = lane >> 4;
  const f32x4 fz = {0.f, 0.f, 0.f, 0.f};
  f32x4 acc[4][4];
#pragma unroll
  for (int i = 0; i < 4; ++i)
#pragma unroll
    for (int j = 0; j < 4; ++j) acc[i][j] = fz;

  const int r0 = tid >> 3;
  const int ch = tid & 7;
  const int sx = (ch ^ (r0 & 7)) << 3;
  // A row -> (b, i) decomposition (b uniform per block since 128 | 512)
  const int ab = m0 >> 9;
  const u16* abase = abuf + (size_t)ab * 8 * 16384;
  const int dA0 = (ch & 3) * 8;

  for (int k0 = 0; k0 < 256; k0 += 64) {
    const int hA0 = (k0 >> 5) + (ch >> 2);
    uint4 gaq[4];
    float4 gb[4][2];
#pragma unroll
    for (int rr = 0; rr < 4; ++rr) {
      const int r = r0 + rr * 32;
      gaq[rr] = *reinterpret_cast<const uint4*>(
          abase + ((size_t)hA0 * 512 + ((m0 & 511) + r)) * 32 + dA0);
      const float* bx = w + (size_t)(n0 + r) * 256 + k0 + ch * 8;
      gb[rr][0] = *reinterpret_cast<const float4*>(bx);
      gb[rr][1] = *reinterpret_cast<const float4*>(bx + 4);
    }
    __syncthreads();
#pragma unroll
    for (int rr = 0; rr < 4; ++rr) {
      const int r = r0 + rr * 32;
      *reinterpret_cast<uint4*>(&As[r * 64 + sx]) = gaq[rr];
      uint4 pk;
      pk.x = cvt_pk_bf16(gb[rr][0].x, gb[rr][0].y);
      pk.y = cvt_pk_bf16(gb[rr][0].z, gb[rr][0].w);
      pk.z = cvt_pk_bf16(gb[rr][1].x, gb[rr][1].y);
      pk.w = cvt_pk_bf16(gb[rr][1].z, gb[rr][1].w);
      *reinterpret_cast<uint4*>(&Bs[r * 64 + sx]) = pk;
    }
    __syncthreads();
#pragma unroll
    for (int ks = 0; ks < 2; ++ks) {
      bf16x8 xf[4], wf[4];
#pragma unroll
      for (int mt = 0; mt < 4; ++mt) {
        const int row = wm * 64 + mt * 16 + lq;
        xf[mt] = *reinterpret_cast<const bf16x8*>(
            &As[row * 64 + (((ks * 4 + g) ^ (row & 7)) << 3)]);
      }
#pragma unroll
      for (int nt = 0; nt < 4; ++nt) {
        const int row = wn * 64 + nt * 16 + lq;
        wf[nt] = *reinterpret_cast<const bf16x8*>(
            &Bs[row * 64 + (((ks * 4 + g) ^ (row & 7)) << 3)]);
      }
#pragma unroll
      for (int mt = 0; mt < 4; ++mt)
#pragma unroll
        for (int nt = 0; nt < 4; ++nt)
          acc[mt][nt] = __builtin_amdgcn_mfma_f32_16x16x32_bf16(
              wf[nt], xf[mt], acc[mt][nt], 0, 0, 0);
    }
  }
  // epilogue: f32 out, row-major, +bias
#pragma unroll
  for (int mt = 0; mt < 4; ++mt) {
    const int m = m0 + wm * 64 + mt * 16 + lq;
#pragma unroll
    for (int nt = 0; nt < 4; ++nt) {
      const int n = n0 + wn * 64 + nt * 16 + 4 * g;
      const float4 pb4 = *reinterpret_cast<const float4*>(pb + n);
      *reinterpret_cast<float4*>(out + (size_t)m * 256 + n) =
          make_float4(acc[mt][nt][0] + pb4.x, acc[mt][nt][1] + pb4.y,
                      acc[mt][nt][2] + pb4.z, acc[mt][nt][3] + pb4.w);
    }
  }
}

extern "C" void kernel_launch(void* const* d_in, const int* in_sizes, int n_in,
                              void* d_out, int out_size, void* d_ws, size_t ws_size,
                              hipStream_t stream) {
  const float* x = (const float*)d_in[0];
  const float* mask = (const float*)d_in[1];
  const float* qkv_w = (const float*)d_in[2];
  const float* proj_w = (const float*)d_in[3];
  const float* proj_b = (const float*)d_in[4];
  const float* cpb_w1 = (const float*)d_in[5];
  const float* cpb_b1 = (const float*)d_in[6];
  const float* cpb_w2 = (const float*)d_in[7];
  const float* rpb = (const float*)d_in[8];
  const int* rpb_idx = (const int*)d_in[9];
  float* out = (float*)d_out;

  char* ws = (char*)d_ws;
  u16* qbuf = (u16*)(ws);                       // 33,554,432 B
  u16* kbuf = (u16*)(ws + 33554432);            // 33,554,432 B
  u16* vbuf = (u16*)(ws + 67108864);            // 33,554,432 B
  u16* cmb = (u16*)(ws + 100663296);            // 67,108,864 B
  float* table16 = (float*)(ws + 167772160);    //    108,000 B

  cpb_kernel<<<3375, 512, 0, stream>>>(rpb, cpb_w1, cpb_b1, cpb_w2, table16);
  cmb_kernel<<<dim3(1024, 128), 256, 0, stream>>>(rpb_idx, table16, mask, cmb);
  qkv_mfma<<<dim3(6, 512), 256, 0, stream>>>(x, qkv_w, qbuf, kbuf, vbuf);
  attn_mfma<<<dim3(2, 8, 128), 256, 0, stream>>>(qbuf, kbuf, vbuf, cmb);
  proj_mfma<<<dim3(2, 512), 256, 0, stream>>>(qbuf, proj_w, proj_b, out);
}

// Round 9
// 320.527 us; speedup vs baseline: 3.5379x; 1.0009x over previous
//
#include <hip/hip_runtime.h>
#include <hip/hip_bf16.h>

// WindowAttention: B=128 windows, N=512, C=256, H=8, D=32.
// Round 9: attn_mfma restored byte-for-byte to the R6-proven version (two
// structural variants NaN'd inexplicably — suspected codegen interaction).
// New this round: qkv XCD-chunked grid swizzle (x-tile L2 reuse) and
// vectorized cmb (8 elem/thread).
// ws layout (bytes):
//   qbuf  bf16 (B,H,N,D)  @ 0           33,554,432  (q pre-scaled by 1/sqrt(32)*log2e; overwritten by attn out)
//   kbuf  bf16 (B,H,N,D)  @ 33,554,432  33,554,432
//   vbuf  bf16 (B,H,N,D)  @ 67,108,864  33,554,432
//   cmb   bf16 (16,8,N,N) @ 100,663,296 67,108,864  (16*sigmoid*log2e + mask*log2e - 11.65, centered)
//   tbl   f32  (3375,8)   @ 167,772,160    108,000
// total ~167.9 MB

using u16 = unsigned short;
using u32 = unsigned int;
typedef short bf16x4 __attribute__((ext_vector_type(4)));
typedef short bf16x8 __attribute__((ext_vector_type(8)));
typedef float f32x4 __attribute__((ext_vector_type(4)));

#define QSL 0.25503471f       // (1/sqrt(32)) * log2(e)
#define LOG2E 1.44269504f
#define CMB_SHIFT 11.65f      // centers bias*log2e (~11.66); softmax shift-invariant

static __device__ __forceinline__ u32 cvt_pk_bf16(float lo, float hi) {
  u32 r;
  asm("v_cvt_pk_bf16_f32 %0, %1, %2" : "=v"(r) : "v"(lo), "v"(hi));
  return r;
}

// ---------------- kernel 1: CPB MLP -> 16*sigmoid*log2e table ----------------
__global__ __launch_bounds__(512) void cpb_kernel(
    const float* __restrict__ rpb, const float* __restrict__ w1,
    const float* __restrict__ b1, const float* __restrict__ w2,
    float* __restrict__ table16) {
  __shared__ float hid[512];
  const int p = blockIdx.x;   // 0..3374
  const int t = threadIdx.x;  // 0..511
  const float r0 = rpb[p * 3 + 0], r1 = rpb[p * 3 + 1], r2 = rpb[p * 3 + 2];
  float hv = fmaf(r0, w1[t * 3 + 0],
             fmaf(r1, w1[t * 3 + 1],
             fmaf(r2, w1[t * 3 + 2], b1[t])));
  hid[t] = fmaxf(hv, 0.0f);
  __syncthreads();
  const int h = t >> 6, lane = t & 63;  // 8 waves, one head per wave
  float s = 0.0f;
#pragma unroll
  for (int u = 0; u < 8; ++u)
    s = fmaf(hid[lane + u * 64], w2[h * 512 + lane + u * 64], s);
#pragma unroll
  for (int off = 32; off > 0; off >>= 1) s += __shfl_down(s, off);
  if (lane == 0) table16[p * 8 + h] = 23.08312065f / (1.0f + __expf(-s));  // 16*log2e*sigmoid
}

// ---------------- kernel 2: combined centered bias+mask (bf16), 8 elem/thread ----------------
__global__ __launch_bounds__(256) void cmb_kernel(
    const int* __restrict__ rpb_idx, const float* __restrict__ table16,
    const float* __restrict__ mask, u16* __restrict__ cmb) {
  const int ij0 = (blockIdx.x * 256 + threadIdx.x) * 8;  // 0..262136, grid.x=128
  const int wh = blockIdx.y;                             // w*8+h
  const int w = wh >> 3, hh = wh & 7;
  const float4 m0 = *reinterpret_cast<const float4*>(mask + (size_t)w * 262144 + ij0);
  const float4 m1 = *reinterpret_cast<const float4*>(mask + (size_t)w * 262144 + ij0 + 4);
  const int4 i0 = *reinterpret_cast<const int4*>(rpb_idx + ij0);
  const int4 i1 = *reinterpret_cast<const int4*>(rpb_idx + ij0 + 4);
  float v0 = table16[i0.x * 8 + hh] + m0.x * LOG2E - CMB_SHIFT;
  float v1 = table16[i0.y * 8 + hh] + m0.y * LOG2E - CMB_SHIFT;
  float v2 = table16[i0.z * 8 + hh] + m0.z * LOG2E - CMB_SHIFT;
  float v3 = table16[i0.w * 8 + hh] + m0.w * LOG2E - CMB_SHIFT;
  float v4 = table16[i1.x * 8 + hh] + m1.x * LOG2E - CMB_SHIFT;
  float v5 = table16[i1.y * 8 + hh] + m1.y * LOG2E - CMB_SHIFT;
  float v6 = table16[i1.z * 8 + hh] + m1.z * LOG2E - CMB_SHIFT;
  float v7 = table16[i1.w * 8 + hh] + m1.w * LOG2E - CMB_SHIFT;
  uint4 pk;
  pk.x = cvt_pk_bf16(v0, v1);
  pk.y = cvt_pk_bf16(v2, v3);
  pk.z = cvt_pk_bf16(v4, v5);
  pk.w = cvt_pk_bf16(v6, v7);
  *reinterpret_cast<uint4*>(cmb + (size_t)wh * 262144 + ij0) = pk;
}

// ---------------- kernel 3: qkv GEMM, bf16 MFMA ----------------
// out[m][n] = sum_k x[m][k]*w[n][k], M=65536, N=768, K=256.
// 128x128 tile, BK=64, 4 waves 2x2 (wave tile 64x64), 16x16x32 MFMA.
// XCD-chunked swizzle: XCD x owns work ids [x*384,(x+1)*384) enumerated
// bn-fastest -> x-tile read once from HBM, 5/6 reads are L2 hits.
__global__ __launch_bounds__(256) void qkv_mfma(
    const float* __restrict__ x, const float* __restrict__ w,
    u16* __restrict__ qbuf, u16* __restrict__ kbuf, u16* __restrict__ vbuf) {
  __shared__ u16 As[128 * 64];
  __shared__ u16 Bs[128 * 64];
  const int tid = threadIdx.x;
  const int flat = blockIdx.x;                  // 0..3071
  const int wrk = (flat & 7) * 384 + (flat >> 3);
  const int bm = wrk / 6;                       // 0..511
  const int bn = wrk - bm * 6;                  // 0..5
  const int m0 = bm * 128, n0 = bn * 128;
  const float scl = (bn < 2) ? QSL : 1.0f;
  const int lane = tid & 63, wid = tid >> 6;
  const int wm = wid >> 1, wn = wid & 1;
  const int lq = lane & 15, g = lane >> 4;
  const f32x4 fz = {0.f, 0.f, 0.f, 0.f};
  f32x4 acc[4][4];
#pragma unroll
  for (int i = 0; i < 4; ++i)
#pragma unroll
    for (int j = 0; j < 4; ++j) acc[i][j] = fz;

  const int r0 = tid >> 3;                      // 0..31
  const int ch = tid & 7;                       // 16B chunk within row
  const int sx = (ch ^ (r0 & 7)) << 3;          // swizzled u16 offset (const: rr*32 keeps row&7)

  for (int k0 = 0; k0 < 256; k0 += 64) {
    float4 ga[4][2], gb[4][2];
#pragma unroll
    for (int rr = 0; rr < 4; ++rr) {
      const int r = r0 + rr * 32;
      const float* ax = x + (size_t)(m0 + r) * 256 + k0 + ch * 8;
      ga[rr][0] = *reinterpret_cast<const float4*>(ax);
      ga[rr][1] = *reinterpret_cast<const float4*>(ax + 4);
      const float* bx = w + (size_t)(n0 + r) * 256 + k0 + ch * 8;
      gb[rr][0] = *reinterpret_cast<const float4*>(bx);
      gb[rr][1] = *reinterpret_cast<const float4*>(bx + 4);
    }
    __syncthreads();  // prior-iter LDS reads done
#pragma unroll
    for (int rr = 0; rr < 4; ++rr) {
      const int r = r0 + rr * 32;
      uint4 pk;
      pk.x = cvt_pk_bf16(ga[rr][0].x, ga[rr][0].y);
      pk.y = cvt_pk_bf16(ga[rr][0].z, ga[rr][0].w);
      pk.z = cvt_pk_bf16(ga[rr][1].x, ga[rr][1].y);
      pk.w = cvt_pk_bf16(ga[rr][1].z, ga[rr][1].w);
      *reinterpret_cast<uint4*>(&As[r * 64 + sx]) = pk;
      pk.x = cvt_pk_bf16(gb[rr][0].x * scl, gb[rr][0].y * scl);
      pk.y = cvt_pk_bf16(gb[rr][0].z * scl, gb[rr][0].w * scl);
      pk.z = cvt_pk_bf16(gb[rr][1].x * scl, gb[rr][1].y * scl);
      pk.w = cvt_pk_bf16(gb[rr][1].z * scl, gb[rr][1].w * scl);
      *reinterpret_cast<uint4*>(&Bs[r * 64 + sx]) = pk;
    }
    __syncthreads();
#pragma unroll
    for (int ks = 0; ks < 2; ++ks) {
      bf16x8 xf[4], wf[4];
#pragma unroll
      for (int mt = 0; mt < 4; ++mt) {
        const int row = wm * 64 + mt * 16 + lq;
        xf[mt] = *reinterpret_cast<const bf16x8*>(
            &As[row * 64 + (((ks * 4 + g) ^ (row & 7)) << 3)]);
      }
#pragma unroll
      for (int nt = 0; nt < 4; ++nt) {
        const int row = wn * 64 + nt * 16 + lq;
        wf[nt] = *reinterpret_cast<const bf16x8*>(
            &Bs[row * 64 + (((ks * 4 + g) ^ (row & 7)) << 3)]);
      }
#pragma unroll
      for (int mt = 0; mt < 4; ++mt)
#pragma unroll
        for (int nt = 0; nt < 4; ++nt)
          acc[mt][nt] = __builtin_amdgcn_mfma_f32_16x16x32_bf16(
              wf[nt], xf[mt], acc[mt][nt], 0, 0, 0);
    }
  }
  // epilogue: lane holds out[m][n=..+4g+r] (acc[mt][nt][r]), scatter bf16 to (b,h,i,d)
  const int sec = bn >> 1;  // 0=q,1=k,2=v (uniform per block)
  u16* dst = sec == 0 ? qbuf : (sec == 1 ? kbuf : vbuf);
#pragma unroll
  for (int mt = 0; mt < 4; ++mt) {
    const int m = m0 + wm * 64 + mt * 16 + lq;
    const int b = m >> 9, ii = m & 511;
#pragma unroll
    for (int nt = 0; nt < 4; ++nt) {
      const int n = n0 + wn * 64 + nt * 16 + 4 * g;
      const int h = (n & 255) >> 5;
      const int d = n & 31;
      const size_t off = ((size_t)(b * 8 + h) * 512 + ii) * 32 + d;
      uint2 o2;
      o2.x = cvt_pk_bf16(acc[mt][nt][0], acc[mt][nt][1]);
      o2.y = cvt_pk_bf16(acc[mt][nt][2], acc[mt][nt][3]);
      *reinterpret_cast<uint2*>(dst + off) = o2;
    }
  }
}

// ---------------- kernel 4: MFMA attention (R6-proven, byte-identical) ----------------
__global__ __launch_bounds__(256, 2) void attn_mfma(
    u16* qbuf,  // in: scaled Q; out: attention output (own rows only)
    const u16* __restrict__ kbuf, const u16* __restrict__ vbuf,
    const u16* __restrict__ cmb) {
  __shared__ u16 Klds[512 * 32];   // row-major keys, XOR-swizzled 16B chunks
  __shared__ u16 Vtlds[32 * 512];  // V transposed [d][n], XOR-swizzled
  const int t = threadIdx.x;
  const int qc = blockIdx.x, h = blockIdx.y;
  const int bz = blockIdx.z;
  const int b = ((bz & 15) << 3) | (bz >> 4);  // co-schedule same (b&15) blocks
  const size_t bh = (size_t)b * 8 + h;
  const u16* kb = kbuf + bh * 16384;
  const u16* vb = vbuf + bh * 16384;

#pragma unroll
  for (int c = 0; c < 8; ++c) {
    const int cid = t + c * 256;
    const int key = cid >> 2, ch = cid & 3;
    const uint4 kd = *reinterpret_cast<const uint4*>(kb + cid * 8);
    const int idx = key * 32 + ((ch * 8) ^ (((key >> 1) & 3) << 3));
    *reinterpret_cast<uint4*>(&Klds[idx]) = kd;
  }
#pragma unroll
  for (int r = 0; r < 2; ++r) {
    const int n = t + r * 256;
    const uint4 v0 = *reinterpret_cast<const uint4*>(vb + n * 32);
    const uint4 v1 = *reinterpret_cast<const uint4*>(vb + n * 32 + 8);
    const uint4 v2 = *reinterpret_cast<const uint4*>(vb + n * 32 + 16);
    const uint4 v3 = *reinterpret_cast<const uint4*>(vb + n * 32 + 24);
    const u32 wv16[16] = {v0.x, v0.y, v0.z, v0.w, v1.x, v1.y, v1.z, v1.w,
                          v2.x, v2.y, v2.z, v2.w, v3.x, v3.y, v3.z, v3.w};
#pragma unroll
    for (int u = 0; u < 16; ++u) {
      const int d0 = 2 * u, d1 = 2 * u + 1;
      Vtlds[d0 * 512 + (n ^ ((d0 & 7) << 3))] = (u16)(wv16[u] & 0xffffu);
      Vtlds[d1 * 512 + (n ^ ((d1 & 7) << 3))] = (u16)(wv16[u] >> 16);
    }
  }
  __syncthreads();

  const int lane = t & 63;
  const int lq = lane & 15, g = lane >> 4;
  const int wv = t >> 6;
  const int q0 = qc * 256 + wv * 64;

  bf16x8 Qf[4];
  u16* qrowbase = qbuf + bh * 16384;
#pragma unroll
  for (int qt = 0; qt < 4; ++qt)
    Qf[qt] = *reinterpret_cast<const bf16x8*>(qrowbase + (q0 + qt * 16 + lq) * 32 + g * 8);

  const u16* cmbp[4];
  const size_t whbase = (size_t)((b & 15) * 8 + h) * 262144;
#pragma unroll
  for (int qt = 0; qt < 4; ++qt)
    cmbp[qt] = cmb + whbase + (size_t)(q0 + qt * 16 + lq) * 512 + 4 * g;

  const f32x4 fzero = {0.f, 0.f, 0.f, 0.f};
  f32x4 o[2][4];
  f32x4 lsum4[4];
#pragma unroll
  for (int qt = 0; qt < 4; ++qt) {
    lsum4[qt] = fzero;
    o[0][qt] = fzero;
    o[1][qt] = fzero;
  }

  for (int j0 = 0; j0 < 512; j0 += 64) {
    bf16x8 Ak[4];
#pragma unroll
    for (int kt = 0; kt < 4; ++kt) {
      const int key = j0 + kt * 16 + lq;
      const int idx = key * 32 + ((g * 8) ^ (((key >> 1) & 3) << 3));
      Ak[kt] = *reinterpret_cast<const bf16x8*>(&Klds[idx]);
    }
    f32x4 s[4][4];
#pragma unroll
    for (int kt = 0; kt < 4; ++kt)
#pragma unroll
      for (int qt = 0; qt < 4; ++qt) {
        const uint2 cc = *reinterpret_cast<const uint2*>(cmbp[qt] + j0 + kt * 16);
        f32x4 ci;
        ci[0] = __uint_as_float((cc.x & 0xffffu) << 16);
        ci[1] = __uint_as_float(cc.x & 0xffff0000u);
        ci[2] = __uint_as_float((cc.y & 0xffffu) << 16);
        ci[3] = __uint_as_float(cc.y & 0xffff0000u);
        s[kt][qt] = __builtin_amdgcn_mfma_f32_16x16x32_bf16(Ak[kt], Qf[qt], ci, 0, 0, 0);
      }
#pragma unroll
    for (int kt = 0; kt < 4; ++kt) {
      bf16x4 Av[2];
#pragma unroll
      for (int dt = 0; dt < 2; ++dt) {
        const int d = dt * 16 + lq;
        const int n0 = j0 + kt * 16 + 4 * g;
        const int idx = d * 512 + (n0 ^ ((d & 7) << 3));
        Av[dt] = *reinterpret_cast<const bf16x4*>(&Vtlds[idx]);
      }
#pragma unroll
      for (int qt = 0; qt < 4; ++qt) {
        f32x4 p = s[kt][qt];
        p[0] = __builtin_amdgcn_exp2f(p[0]);
        p[1] = __builtin_amdgcn_exp2f(p[1]);
        p[2] = __builtin_amdgcn_exp2f(p[2]);
        p[3] = __builtin_amdgcn_exp2f(p[3]);
        lsum4[qt] += p;
        union { u32 u[2]; bf16x4 v; } bp;
        bp.u[0] = cvt_pk_bf16(p[0], p[1]);
        bp.u[1] = cvt_pk_bf16(p[2], p[3]);
        o[0][qt] = __builtin_amdgcn_mfma_f32_16x16x16bf16_1k(Av[0], bp.v, o[0][qt], 0, 0, 0);
        o[1][qt] = __builtin_amdgcn_mfma_f32_16x16x16bf16_1k(Av[1], bp.v, o[1][qt], 0, 0, 0);
      }
    }
  }
#pragma unroll
  for (int qt = 0; qt < 4; ++qt) {
    float l = (lsum4[qt][0] + lsum4[qt][1]) + (lsum4[qt][2] + lsum4[qt][3]);
    l += __shfl_xor(l, 16);
    l += __shfl_xor(l, 32);
    const float inv = 1.0f / l;
    u16* orow = qrowbase + (q0 + qt * 16 + lq) * 32;
#pragma unroll
    for (int dt = 0; dt < 2; ++dt) {
      uint2 w2;
      w2.x = cvt_pk_bf16(o[dt][qt][0] * inv, o[dt][qt][1] * inv);
      w2.y = cvt_pk_bf16(o[dt][qt][2] * inv, o[dt][qt][3] * inv);
      *reinterpret_cast<uint2*>(orow + dt * 16 + 4 * g) = w2;
    }
  }
}

// ---------------- kernel 5: proj GEMM, bf16 MFMA ----------------
// out[m][n] = sum_c attnout[m][c]*proj_w[n][c] + pb[n], M=65536, N=256, K=256.
// A source is bf16 in scattered (b,h,i,d) layout (qbuf after attention).
__global__ __launch_bounds__(256) void proj_mfma(
    const u16* __restrict__ abuf, const float* __restrict__ w,
    const float* __restrict__ pb, float* __restrict__ out) {
  __shared__ u16 As[128 * 64];
  __shared__ u16 Bs[128 * 64];
  const int tid = threadIdx.x;
  const int bn = blockIdx.x;  // 0..1
  const int bm = blockIdx.y;  // 0..511
  const int m0 = bm * 128, n0 = bn * 128;
  const int lane = tid & 63, wid = tid >> 6;
  const int wm = wid >> 1, wn = wid & 1;
  const int lq = lane & 15, g = lane >> 4;
  const f32x4 fz = {0.f, 0.f, 0.f, 0.f};
  f32x4 acc[4][4];
#pragma unroll
  for (int i = 0; i < 4; ++i)
#pragma unroll
    for (int j = 0; j < 4; ++j) acc[i][j] = fz;

  const int r0 = tid >> 3;
  const int ch = tid & 7;
  const int sx = (ch ^ (r0 & 7)) << 3;
  // A row -> (b, i) decomposition (b uniform per block since 128 | 512)
  const int ab = m0 >> 9;
  const u16* abase = abuf + (size_t)ab * 8 * 16384;
  const int dA0 = (ch & 3) * 8;

  for (int k0 = 0; k0 < 256; k0 += 64) {
    const int hA0 = (k0 >> 5) + (ch >> 2);
    uint4 gaq[4];
    float4 gb[4][2];
#pragma unroll
    for (int rr = 0; rr < 4; ++rr) {
      const int r = r0 + rr * 32;
      gaq[rr] = *reinterpret_cast<const uint4*>(
          abase + ((size_t)hA0 * 512 + ((m0 & 511) + r)) * 32 + dA0);
      const float* bx = w + (size_t)(n0 + r) * 256 + k0 + ch * 8;
      gb[rr][0] = *reinterpret_cast<const float4*>(bx);
      gb[rr][1] = *reinterpret_cast<const float4*>(bx + 4);
    }
    __syncthreads();
#pragma unroll
    for (int rr = 0; rr < 4; ++rr) {
      const int r = r0 + rr * 32;
      *reinterpret_cast<uint4*>(&As[r * 64 + sx]) = gaq[rr];
      uint4 pk;
      pk.x = cvt_pk_bf16(gb[rr][0].x, gb[rr][0].y);
      pk.y = cvt_pk_bf16(gb[rr][0].z, gb[rr][0].w);
      pk.z = cvt_pk_bf16(gb[rr][1].x, gb[rr][1].y);
      pk.w = cvt_pk_bf16(gb[rr][1].z, gb[rr][1].w);
      *reinterpret_cast<uint4*>(&Bs[r * 64 + sx]) = pk;
    }
    __syncthreads();
#pragma unroll
    for (int ks = 0; ks < 2; ++ks) {
      bf16x8 xf[4], wf[4];
#pragma unroll
      for (int mt = 0; mt < 4; ++mt) {
        const int row = wm * 64 + mt * 16 + lq;
        xf[mt] = *reinterpret_cast<const bf16x8*>(
            &As[row * 64 + (((ks * 4 + g) ^ (row & 7)) << 3)]);
      }
#pragma unroll
      for (int nt = 0; nt < 4; ++nt) {
        const int row = wn * 64 + nt * 16 + lq;
        wf[nt] = *reinterpret_cast<const bf16x8*>(
            &Bs[row * 64 + (((ks * 4 + g) ^ (row & 7)) << 3)]);
      }
#pragma unroll
      for (int mt = 0; mt < 4; ++mt)
#pragma unroll
        for (int nt = 0; nt < 4; ++nt)
          acc[mt][nt] = __builtin_amdgcn_mfma_f32_16x16x32_bf16(
              wf[nt], xf[mt], acc[mt][nt], 0, 0, 0);
    }
  }
  // epilogue: f32 out, row-major, +bias
#pragma unroll
  for (int mt = 0; mt < 4; ++mt) {
    const int m = m0 + wm * 64 + mt * 16 + lq;
#pragma unroll
    for (int nt = 0; nt < 4; ++nt) {
      const int n = n0 + wn * 64 + nt * 16 + 4 * g;
      const float4 pb4 = *reinterpret_cast<const float4*>(pb + n);
      *reinterpret_cast<float4*>(out + (size_t)m * 256 + n) =
          make_float4(acc[mt][nt][0] + pb4.x, acc[mt][nt][1] + pb4.y,
                      acc[mt][nt][2] + pb4.z, acc[mt][nt][3] + pb4.w);
    }
  }
}

extern "C" void kernel_launch(void* const* d_in, const int* in_sizes, int n_in,
                              void* d_out, int out_size, void* d_ws, size_t ws_size,
                              hipStream_t stream) {
  const float* x = (const float*)d_in[0];
  const float* mask = (const float*)d_in[1];
  const float* qkv_w = (const float*)d_in[2];
  const float* proj_w = (const float*)d_in[3];
  const float* proj_b = (const float*)d_in[4];
  const float* cpb_w1 = (const float*)d_in[5];
  const float* cpb_b1 = (const float*)d_in[6];
  const float* cpb_w2 = (const float*)d_in[7];
  const float* rpb = (const float*)d_in[8];
  const int* rpb_idx = (const int*)d_in[9];
  float* out = (float*)d_out;

  char* ws = (char*)d_ws;
  u16* qbuf = (u16*)(ws);                       // 33,554,432 B
  u16* kbuf = (u16*)(ws + 33554432);            // 33,554,432 B
  u16* vbuf = (u16*)(ws + 67108864);            // 33,554,432 B
  u16* cmb = (u16*)(ws + 100663296);            // 67,108,864 B
  float* table16 = (float*)(ws + 167772160);    //    108,000 B

  cpb_kernel<<<3375, 512, 0, stream>>>(rpb, cpb_w1, cpb_b1, cpb_w2, table16);
  cmb_kernel<<<dim3(128, 128), 256, 0, stream>>>(rpb_idx, table16, mask, cmb);
  qkv_mfma<<<3072, 256, 0, stream>>>(x, qkv_w, qbuf, kbuf, vbuf);
  attn_mfma<<<dim3(2, 8, 128), 256, 0, stream>>>(qbuf, kbuf, vbuf, cmb);
  proj_mfma<<<dim3(2, 512), 256, 0, stream>>>(qbuf, proj_w, proj_b, out);
}

// Round 11
// 287.357 us; speedup vs baseline: 3.9463x; 1.1154x over previous
//
#include <hip/hip_runtime.h>
#include <hip/hip_bf16.h>

// WindowAttention: B=128 windows, N=512, C=256, H=8, D=32.
// Round 11: attn_mfma FROZEN byte-identical to R6/R9 (3 structural edits NaN'd
// unexplainably). Safe wins elsewhere: one-pass cmb (mask read once for all 8
// heads), software-prefetched qkv/proj GEMMs (load next K-step before compute).
// ws layout (bytes):
//   qbuf  bf16 (B,H,N,D)  @ 0           33,554,432  (q pre-scaled by 1/sqrt(32)*log2e; overwritten by attn out)
//   kbuf  bf16 (B,H,N,D)  @ 33,554,432  33,554,432
//   vbuf  bf16 (B,H,N,D)  @ 67,108,864  33,554,432
//   cmb   bf16 (16,8,N,N) @ 100,663,296 67,108,864  (16*sigmoid*log2e + mask*log2e - 11.65, centered)
//   tbl   f32  (3375,8)   @ 167,772,160    108,000
// total ~167.9 MB

using u16 = unsigned short;
using u32 = unsigned int;
typedef short bf16x4 __attribute__((ext_vector_type(4)));
typedef short bf16x8 __attribute__((ext_vector_type(8)));
typedef float f32x4 __attribute__((ext_vector_type(4)));

#define QSL 0.25503471f       // (1/sqrt(32)) * log2(e)
#define LOG2E 1.44269504f
#define CMB_SHIFT 11.65f      // centers bias*log2e (~11.66); softmax shift-invariant

static __device__ __forceinline__ u32 cvt_pk_bf16(float lo, float hi) {
  u32 r;
  asm("v_cvt_pk_bf16_f32 %0, %1, %2" : "=v"(r) : "v"(lo), "v"(hi));
  return r;
}

// ---------------- kernel 1: CPB MLP -> 16*sigmoid*log2e table ----------------
__global__ __launch_bounds__(512) void cpb_kernel(
    const float* __restrict__ rpb, const float* __restrict__ w1,
    const float* __restrict__ b1, const float* __restrict__ w2,
    float* __restrict__ table16) {
  __shared__ float hid[512];
  const int p = blockIdx.x;   // 0..3374
  const int t = threadIdx.x;  // 0..511
  const float r0 = rpb[p * 3 + 0], r1 = rpb[p * 3 + 1], r2 = rpb[p * 3 + 2];
  float hv = fmaf(r0, w1[t * 3 + 0],
             fmaf(r1, w1[t * 3 + 1],
             fmaf(r2, w1[t * 3 + 2], b1[t])));
  hid[t] = fmaxf(hv, 0.0f);
  __syncthreads();
  const int h = t >> 6, lane = t & 63;  // 8 waves, one head per wave
  float s = 0.0f;
#pragma unroll
  for (int u = 0; u < 8; ++u)
    s = fmaf(hid[lane + u * 64], w2[h * 512 + lane + u * 64], s);
#pragma unroll
  for (int off = 32; off > 0; off >>= 1) s += __shfl_down(s, off);
  if (lane == 0) table16[p * 8 + h] = 23.08312065f / (1.0f + __expf(-s));  // 16*log2e*sigmoid
}

// ---------------- kernel 2: combined centered bias+mask (bf16), one-pass ----------------
// grid (256, 16): thread handles 4 ij positions for ALL 8 heads of window w.
// mask/idx read once; table rows loaded as float4 pairs; per-plane coalesced stores.
__global__ __launch_bounds__(256) void cmb_kernel(
    const int* __restrict__ rpb_idx, const float* __restrict__ table16,
    const float* __restrict__ mask, u16* __restrict__ cmb) {
  const int ij0 = (blockIdx.x * 256 + threadIdx.x) * 4;  // 0..262140
  const int w = blockIdx.y;                              // 0..15
  const float4 m4 = *reinterpret_cast<const float4*>(mask + (size_t)w * 262144 + ij0);
  const int4 i4 = *reinterpret_cast<const int4*>(rpb_idx + ij0);
  float ta[8], tb[8], tc[8], td[8];
  *reinterpret_cast<float4*>(&ta[0]) = *reinterpret_cast<const float4*>(table16 + i4.x * 8);
  *reinterpret_cast<float4*>(&ta[4]) = *reinterpret_cast<const float4*>(table16 + i4.x * 8 + 4);
  *reinterpret_cast<float4*>(&tb[0]) = *reinterpret_cast<const float4*>(table16 + i4.y * 8);
  *reinterpret_cast<float4*>(&tb[4]) = *reinterpret_cast<const float4*>(table16 + i4.y * 8 + 4);
  *reinterpret_cast<float4*>(&tc[0]) = *reinterpret_cast<const float4*>(table16 + i4.z * 8);
  *reinterpret_cast<float4*>(&tc[4]) = *reinterpret_cast<const float4*>(table16 + i4.z * 8 + 4);
  *reinterpret_cast<float4*>(&td[0]) = *reinterpret_cast<const float4*>(table16 + i4.w * 8);
  *reinterpret_cast<float4*>(&td[4]) = *reinterpret_cast<const float4*>(table16 + i4.w * 8 + 4);
  const float b0 = m4.x * LOG2E - CMB_SHIFT;
  const float b1 = m4.y * LOG2E - CMB_SHIFT;
  const float b2 = m4.z * LOG2E - CMB_SHIFT;
  const float b3 = m4.w * LOG2E - CMB_SHIFT;
  u16* outp = cmb + (size_t)w * 8 * 262144 + ij0;
#pragma unroll
  for (int h = 0; h < 8; ++h) {
    uint2 o;
    o.x = cvt_pk_bf16(ta[h] + b0, tb[h] + b1);
    o.y = cvt_pk_bf16(tc[h] + b2, td[h] + b3);
    *reinterpret_cast<uint2*>(outp + (size_t)h * 262144) = o;
  }
}

// ---------------- kernel 3: qkv GEMM, bf16 MFMA, prefetched ----------------
// out[m][n] = sum_k x[m][k]*w[n][k], M=65536, N=768, K=256.
// 128x128 tile, BK=64, 4 waves 2x2, 16x16x32 MFMA, XCD-chunked swizzle.
// Next K-step's global loads issued BEFORE the compute phase (latency hiding).
__global__ __launch_bounds__(256) void qkv_mfma(
    const float* __restrict__ x, const float* __restrict__ w,
    u16* __restrict__ qbuf, u16* __restrict__ kbuf, u16* __restrict__ vbuf) {
  __shared__ u16 As[128 * 64];
  __shared__ u16 Bs[128 * 64];
  const int tid = threadIdx.x;
  const int flat = blockIdx.x;                  // 0..3071
  const int wrk = (flat & 7) * 384 + (flat >> 3);
  const int bm = wrk / 6;                       // 0..511
  const int bn = wrk - bm * 6;                  // 0..5
  const int m0 = bm * 128, n0 = bn * 128;
  const float scl = (bn < 2) ? QSL : 1.0f;
  const int lane = tid & 63, wid = tid >> 6;
  const int wm = wid >> 1, wn = wid & 1;
  const int lq = lane & 15, g = lane >> 4;
  const f32x4 fz = {0.f, 0.f, 0.f, 0.f};
  f32x4 acc[4][4];
#pragma unroll
  for (int i = 0; i < 4; ++i)
#pragma unroll
    for (int j = 0; j < 4; ++j) acc[i][j] = fz;

  const int r0 = tid >> 3;                      // 0..31
  const int ch = tid & 7;                       // 16B chunk within row
  const int sx = (ch ^ (r0 & 7)) << 3;          // swizzled u16 offset (const: rr*32 keeps row&7)

  float4 ga[4][2], gb[4][2];
  auto gload = [&](int k0) {
#pragma unroll
    for (int rr = 0; rr < 4; ++rr) {
      const int r = r0 + rr * 32;
      const float* ax = x + (size_t)(m0 + r) * 256 + k0 + ch * 8;
      ga[rr][0] = *reinterpret_cast<const float4*>(ax);
      ga[rr][1] = *reinterpret_cast<const float4*>(ax + 4);
      const float* bx = w + (size_t)(n0 + r) * 256 + k0 + ch * 8;
      gb[rr][0] = *reinterpret_cast<const float4*>(bx);
      gb[rr][1] = *reinterpret_cast<const float4*>(bx + 4);
    }
  };

  gload(0);
  for (int k0 = 0; k0 < 256; k0 += 64) {
    __syncthreads();  // prior-iter LDS reads done
#pragma unroll
    for (int rr = 0; rr < 4; ++rr) {
      const int r = r0 + rr * 32;
      uint4 pk;
      pk.x = cvt_pk_bf16(ga[rr][0].x, ga[rr][0].y);
      pk.y = cvt_pk_bf16(ga[rr][0].z, ga[rr][0].w);
      pk.z = cvt_pk_bf16(ga[rr][1].x, ga[rr][1].y);
      pk.w = cvt_pk_bf16(ga[rr][1].z, ga[rr][1].w);
      *reinterpret_cast<uint4*>(&As[r * 64 + sx]) = pk;
      pk.x = cvt_pk_bf16(gb[rr][0].x * scl, gb[rr][0].y * scl);
      pk.y = cvt_pk_bf16(gb[rr][0].z * scl, gb[rr][0].w * scl);
      pk.z = cvt_pk_bf16(gb[rr][1].x * scl, gb[rr][1].y * scl);
      pk.w = cvt_pk_bf16(gb[rr][1].z * scl, gb[rr][1].w * scl);
      *reinterpret_cast<uint4*>(&Bs[r * 64 + sx]) = pk;
    }
    __syncthreads();
    if (k0 + 64 < 256) gload(k0 + 64);  // prefetch next step under compute
#pragma unroll
    for (int ks = 0; ks < 2; ++ks) {
      bf16x8 xf[4], wf[4];
#pragma unroll
      for (int mt = 0; mt < 4; ++mt) {
        const int row = wm * 64 + mt * 16 + lq;
        xf[mt] = *reinterpret_cast<const bf16x8*>(
            &As[row * 64 + (((ks * 4 + g) ^ (row & 7)) << 3)]);
      }
#pragma unroll
      for (int nt = 0; nt < 4; ++nt) {
        const int row = wn * 64 + nt * 16 + lq;
        wf[nt] = *reinterpret_cast<const bf16x8*>(
            &Bs[row * 64 + (((ks * 4 + g) ^ (row & 7)) << 3)]);
      }
#pragma unroll
      for (int mt = 0; mt < 4; ++mt)
#pragma unroll
        for (int nt = 0; nt < 4; ++nt)
          acc[mt][nt] = __builtin_amdgcn_mfma_f32_16x16x32_bf16(
              wf[nt], xf[mt], acc[mt][nt], 0, 0, 0);
    }
  }
  // epilogue: lane holds out[m][n=..+4g+r] (acc[mt][nt][r]), scatter bf16 to (b,h,i,d)
  const int sec = bn >> 1;  // 0=q,1=k,2=v (uniform per block)
  u16* dst = sec == 0 ? qbuf : (sec == 1 ? kbuf : vbuf);
#pragma unroll
  for (int mt = 0; mt < 4; ++mt) {
    const int m = m0 + wm * 64 + mt * 16 + lq;
    const int b = m >> 9, ii = m & 511;
#pragma unroll
    for (int nt = 0; nt < 4; ++nt) {
      const int n = n0 + wn * 64 + nt * 16 + 4 * g;
      const int h = (n & 255) >> 5;
      const int d = n & 31;
      const size_t off = ((size_t)(b * 8 + h) * 512 + ii) * 32 + d;
      uint2 o2;
      o2.x = cvt_pk_bf16(acc[mt][nt][0], acc[mt][nt][1]);
      o2.y = cvt_pk_bf16(acc[mt][nt][2], acc[mt][nt][3]);
      *reinterpret_cast<uint2*>(dst + off) = o2;
    }
  }
}

// ---------------- kernel 4: MFMA attention (R6/R9-proven, FROZEN byte-identical) ----------------
__global__ __launch_bounds__(256, 2) void attn_mfma(
    u16* qbuf,  // in: scaled Q; out: attention output (own rows only)
    const u16* __restrict__ kbuf, const u16* __restrict__ vbuf,
    const u16* __restrict__ cmb) {
  __shared__ u16 Klds[512 * 32];   // row-major keys, XOR-swizzled 16B chunks
  __shared__ u16 Vtlds[32 * 512];  // V transposed [d][n], XOR-swizzled
  const int t = threadIdx.x;
  const int qc = blockIdx.x, h = blockIdx.y;
  const int bz = blockIdx.z;
  const int b = ((bz & 15) << 3) | (bz >> 4);  // co-schedule same (b&15) blocks
  const size_t bh = (size_t)b * 8 + h;
  const u16* kb = kbuf + bh * 16384;
  const u16* vb = vbuf + bh * 16384;

#pragma unroll
  for (int c = 0; c < 8; ++c) {
    const int cid = t + c * 256;
    const int key = cid >> 2, ch = cid & 3;
    const uint4 kd = *reinterpret_cast<const uint4*>(kb + cid * 8);
    const int idx = key * 32 + ((ch * 8) ^ (((key >> 1) & 3) << 3));
    *reinterpret_cast<uint4*>(&Klds[idx]) = kd;
  }
#pragma unroll
  for (int r = 0; r < 2; ++r) {
    const int n = t + r * 256;
    const uint4 v0 = *reinterpret_cast<const uint4*>(vb + n * 32);
    const uint4 v1 = *reinterpret_cast<const uint4*>(vb + n * 32 + 8);
    const uint4 v2 = *reinterpret_cast<const uint4*>(vb + n * 32 + 16);
    const uint4 v3 = *reinterpret_cast<const uint4*>(vb + n * 32 + 24);
    const u32 wv16[16] = {v0.x, v0.y, v0.z, v0.w, v1.x, v1.y, v1.z, v1.w,
                          v2.x, v2.y, v2.z, v2.w, v3.x, v3.y, v3.z, v3.w};
#pragma unroll
    for (int u = 0; u < 16; ++u) {
      const int d0 = 2 * u, d1 = 2 * u + 1;
      Vtlds[d0 * 512 + (n ^ ((d0 & 7) << 3))] = (u16)(wv16[u] & 0xffffu);
      Vtlds[d1 * 512 + (n ^ ((d1 & 7) << 3))] = (u16)(wv16[u] >> 16);
    }
  }
  __syncthreads();

  const int lane = t & 63;
  const int lq = lane & 15, g = lane >> 4;
  const int wv = t >> 6;
  const int q0 = qc * 256 + wv * 64;

  bf16x8 Qf[4];
  u16* qrowbase = qbuf + bh * 16384;
#pragma unroll
  for (int qt = 0; qt < 4; ++qt)
    Qf[qt] = *reinterpret_cast<const bf16x8*>(qrowbase + (q0 + qt * 16 + lq) * 32 + g * 8);

  const u16* cmbp[4];
  const size_t whbase = (size_t)((b & 15) * 8 + h) * 262144;
#pragma unroll
  for (int qt = 0; qt < 4; ++qt)
    cmbp[qt] = cmb + whbase + (size_t)(q0 + qt * 16 + lq) * 512 + 4 * g;

  const f32x4 fzero = {0.f, 0.f, 0.f, 0.f};
  f32x4 o[2][4];
  f32x4 lsum4[4];
#pragma unroll
  for (int qt = 0; qt < 4; ++qt) {
    lsum4[qt] = fzero;
    o[0][qt] = fzero;
    o[1][qt] = fzero;
  }

  for (int j0 = 0; j0 < 512; j0 += 64) {
    bf16x8 Ak[4];
#pragma unroll
    for (int kt = 0; kt < 4; ++kt) {
      const int key = j0 + kt * 16 + lq;
      const int idx = key * 32 + ((g * 8) ^ (((key >> 1) & 3) << 3));
      Ak[kt] = *reinterpret_cast<const bf16x8*>(&Klds[idx]);
    }
    f32x4 s[4][4];
#pragma unroll
    for (int kt = 0; kt < 4; ++kt)
#pragma unroll
      for (int qt = 0; qt < 4; ++qt) {
        const uint2 cc = *reinterpret_cast<const uint2*>(cmbp[qt] + j0 + kt * 16);
        f32x4 ci;
        ci[0] = __uint_as_float((cc.x & 0xffffu) << 16);
        ci[1] = __uint_as_float(cc.x & 0xffff0000u);
        ci[2] = __uint_as_float((cc.y & 0xffffu) << 16);
        ci[3] = __uint_as_float(cc.y & 0xffff0000u);
        s[kt][qt] = __builtin_amdgcn_mfma_f32_16x16x32_bf16(Ak[kt], Qf[qt], ci, 0, 0, 0);
      }
#pragma unroll
    for (int kt = 0; kt < 4; ++kt) {
      bf16x4 Av[2];
#pragma unroll
      for (int dt = 0; dt < 2; ++dt) {
        const int d = dt * 16 + lq;
        const int n0 = j0 + kt * 16 + 4 * g;
        const int idx = d * 512 + (n0 ^ ((d & 7) << 3));
        Av[dt] = *reinterpret_cast<const bf16x4*>(&Vtlds[idx]);
      }
#pragma unroll
      for (int qt = 0; qt < 4; ++qt) {
        f32x4 p = s[kt][qt];
        p[0] = __builtin_amdgcn_exp2f(p[0]);
        p[1] = __builtin_amdgcn_exp2f(p[1]);
        p[2] = __builtin_amdgcn_exp2f(p[2]);
        p[3] = __builtin_amdgcn_exp2f(p[3]);
        lsum4[qt] += p;
        union { u32 u[2]; bf16x4 v; } bp;
        bp.u[0] = cvt_pk_bf16(p[0], p[1]);
        bp.u[1] = cvt_pk_bf16(p[2], p[3]);
        o[0][qt] = __builtin_amdgcn_mfma_f32_16x16x16bf16_1k(Av[0], bp.v, o[0][qt], 0, 0, 0);
        o[1][qt] = __builtin_amdgcn_mfma_f32_16x16x16bf16_1k(Av[1], bp.v, o[1][qt], 0, 0, 0);
      }
    }
  }
#pragma unroll
  for (int qt = 0; qt < 4; ++qt) {
    float l = (lsum4[qt][0] + lsum4[qt][1]) + (lsum4[qt][2] + lsum4[qt][3]);
    l += __shfl_xor(l, 16);
    l += __shfl_xor(l, 32);
    const float inv = 1.0f / l;
    u16* orow = qrowbase + (q0 + qt * 16 + lq) * 32;
#pragma unroll
    for (int dt = 0; dt < 2; ++dt) {
      uint2 w2;
      w2.x = cvt_pk_bf16(o[dt][qt][0] * inv, o[dt][qt][1] * inv);
      w2.y = cvt_pk_bf16(o[dt][qt][2] * inv, o[dt][qt][3] * inv);
      *reinterpret_cast<uint2*>(orow + dt * 16 + 4 * g) = w2;
    }
  }
}

// ---------------- kernel 5: proj GEMM, bf16 MFMA, prefetched ----------------
// out[m][n] = sum_c attnout[m][c]*proj_w[n][c] + pb[n], M=65536, N=256, K=256.
// A source is bf16 in scattered (b,h,i,d) layout (qbuf after attention).
__global__ __launch_bounds__(256) void proj_mfma(
    const u16* __restrict__ abuf, const float* __restrict__ w,
    const float* __restrict__ pb, float* __restrict__ out) {
  __shared__ u16 As[128 * 64];
  __shared__ u16 Bs[128 * 64];
  const int tid = threadIdx.x;
  const int bn = blockIdx.x;  // 0..1
  const int bm = blockIdx.y;  // 0..511
  const int m0 = bm * 128, n0 = bn * 128;
  const int lane = tid & 63, wid = tid >> 6;
  const int wm = wid >> 1, wn = wid & 1;
  const int lq = lane & 15, g = lane >> 4;
  const f32x4 fz = {0.f, 0.f, 0.f, 0.f};
  f32x4 acc[4][4];
#pragma unroll
  for (int i = 0; i < 4; ++i)
#pragma unroll
    for (int j = 0; j < 4; ++j) acc[i][j] = fz;

  const int r0 = tid >> 3;
  const int ch = tid & 7;
  const int sx = (ch ^ (r0 & 7)) << 3;
  // A row -> (b, i) decomposition (b uniform per block since 128 | 512)
  const int ab = m0 >> 9;
  const u16* abase = abuf + (size_t)ab * 8 * 16384;
  const int dA0 = (ch & 3) * 8;

  uint4 gaq[4];
  float4 gb[4][2];
  auto gload = [&](int k0) {
    const int hA0 = (k0 >> 5) + (ch >> 2);
#pragma unroll
    for (int rr = 0; rr < 4; ++rr) {
      const int r = r0 + rr * 32;
      gaq[rr] = *reinterpret_cast<const uint4*>(
          abase + ((size_t)hA0 * 512 + ((m0 & 511) + r)) * 32 + dA0);
      const float* bx = w + (size_t)(n0 + r) * 256 + k0 + ch * 8;
      gb[rr][0] = *reinterpret_cast<const float4*>(bx);
      gb[rr][1] = *reinterpret_cast<const float4*>(bx + 4);
    }
  };

  gload(0);
  for (int k0 = 0; k0 < 256; k0 += 64) {
    __syncthreads();
#pragma unroll
    for (int rr = 0; rr < 4; ++rr) {
      const int r = r0 + rr * 32;
      *reinterpret_cast<uint4*>(&As[r * 64 + sx]) = gaq[rr];
      uint4 pk;
      pk.x = cvt_pk_bf16(gb[rr][0].x, gb[rr][0].y);
      pk.y = cvt_pk_bf16(gb[rr][0].z, gb[rr][0].w);
      pk.z = cvt_pk_bf16(gb[rr][1].x, gb[rr][1].y);
      pk.w = cvt_pk_bf16(gb[rr][1].z, gb[rr][1].w);
      *reinterpret_cast<uint4*>(&Bs[r * 64 + sx]) = pk;
    }
    __syncthreads();
    if (k0 + 64 < 256) gload(k0 + 64);  // prefetch next step under compute
#pragma unroll
    for (int ks = 0; ks < 2; ++ks) {
      bf16x8 xf[4], wf[4];
#pragma unroll
      for (int mt = 0; mt < 4; ++mt) {
        const int row = wm * 64 + mt * 16 + lq;
        xf[mt] = *reinterpret_cast<const bf16x8*>(
            &As[row * 64 + (((ks * 4 + g) ^ (row & 7)) << 3)]);
      }
#pragma unroll
      for (int nt = 0; nt < 4; ++nt) {
        const int row = wn * 64 + nt * 16 + lq;
        wf[nt] = *reinterpret_cast<const bf16x8*>(
            &Bs[row * 64 + (((ks * 4 + g) ^ (row & 7)) << 3)]);
      }
#pragma unroll
      for (int mt = 0; mt < 4; ++mt)
#pragma unroll
        for (int nt = 0; nt < 4; ++nt)
          acc[mt][nt] = __builtin_amdgcn_mfma_f32_16x16x32_bf16(
              wf[nt], xf[mt], acc[mt][nt], 0, 0, 0);
    }
  }
  // epilogue: f32 out, row-major, +bias
#pragma unroll
  for (int mt = 0; mt < 4; ++mt) {
    const int m = m0 + wm * 64 + mt * 16 + lq;
#pragma unroll
    for (int nt = 0; nt < 4; ++nt) {
      const int n = n0 + wn * 64 + nt * 16 + 4 * g;
      const float4 pb4 = *reinterpret_cast<const float4*>(pb + n);
      *reinterpret_cast<float4*>(out + (size_t)m * 256 + n) =
          make_float4(acc[mt][nt][0] + pb4.x, acc[mt][nt][1] + pb4.y,
                      acc[mt][nt][2] + pb4.z, acc[mt][nt][3] + pb4.w);
    }
  }
}

extern "C" void kernel_launch(void* const* d_in, const int* in_sizes, int n_in,
                              void* d_out, int out_size, void* d_ws, size_t ws_size,
                              hipStream_t stream) {
  const float* x = (const float*)d_in[0];
  const float* mask = (const float*)d_in[1];
  const float* qkv_w = (const float*)d_in[2];
  const float* proj_w = (const float*)d_in[3];
  const float* proj_b = (const float*)d_in[4];
  const float* cpb_w1 = (const float*)d_in[5];
  const float* cpb_b1 = (const float*)d_in[6];
  const float* cpb_w2 = (const float*)d_in[7];
  const float* rpb = (const float*)d_in[8];
  const int* rpb_idx = (const int*)d_in[9];
  float* out = (float*)d_out;

  char* ws = (char*)d_ws;
  u16* qbuf = (u16*)(ws);                       // 33,554,432 B
  u16* kbuf = (u16*)(ws + 33554432);            // 33,554,432 B
  u16* vbuf = (u16*)(ws + 67108864);            // 33,554,432 B
  u16* cmb = (u16*)(ws + 100663296);            // 67,108,864 B
  float* table16 = (float*)(ws + 167772160);    //    108,000 B

  cpb_kernel<<<3375, 512, 0, stream>>>(rpb, cpb_w1, cpb_b1, cpb_w2, table16);
  cmb_kernel<<<dim3(256, 16), 256, 0, stream>>>(rpb_idx, table16, mask, cmb);
  qkv_mfma<<<3072, 256, 0, stream>>>(x, qkv_w, qbuf, kbuf, vbuf);
  attn_mfma<<<dim3(2, 8, 128), 256, 0, stream>>>(qbuf, kbuf, vbuf, cmb);
  proj_mfma<<<dim3(2, 512), 256, 0, stream>>>(qbuf, proj_w, proj_b, out);
}

// Round 13
// 275.557 us; speedup vs baseline: 4.1153x; 1.0428x over previous
//
#include <hip/hip_runtime.h>
#include <hip/hip_bf16.h>

// WindowAttention: B=128 windows, N=512, C=256, H=8, D=32.
// Round 13: attn FROZEN byte-identical (4 restructures NaN'd — codegen-sensitive;
// only byte-identical text survives). This round: proj bn-merge — stage the A
// tile once per 128-row block and compute both 128-col output halves (2 Bs
// tiles, 2 acc sets), halving proj's A gather traffic + staging work.
// qkv/cmb/cpb byte-identical to R11 (passed, 287 us).
// ws layout (bytes):
//   qbuf  bf16 (B,H,N,D)  @ 0           33,554,432  (q pre-scaled by 1/sqrt(32)*log2e; overwritten by attn out)
//   kbuf  bf16 (B,H,N,D)  @ 33,554,432  33,554,432
//   vbuf  bf16 (B,H,N,D)  @ 67,108,864  33,554,432
//   cmb   bf16 (16,8,N,N) @ 100,663,296 67,108,864  (16*sigmoid*log2e + mask*log2e - 11.65, centered)
//   tbl   f32  (3375,8)   @ 167,772,160    108,000
// total ~167.9 MB

using u16 = unsigned short;
using u32 = unsigned int;
typedef short bf16x4 __attribute__((ext_vector_type(4)));
typedef short bf16x8 __attribute__((ext_vector_type(8)));
typedef float f32x4 __attribute__((ext_vector_type(4)));

#define QSL 0.25503471f       // (1/sqrt(32)) * log2(e)
#define LOG2E 1.44269504f
#define CMB_SHIFT 11.65f      // centers bias*log2e (~11.66); softmax shift-invariant

static __device__ __forceinline__ u32 cvt_pk_bf16(float lo, float hi) {
  u32 r;
  asm("v_cvt_pk_bf16_f32 %0, %1, %2" : "=v"(r) : "v"(lo), "v"(hi));
  return r;
}

// ---------------- kernel 1: CPB MLP -> 16*sigmoid*log2e table ----------------
__global__ __launch_bounds__(512) void cpb_kernel(
    const float* __restrict__ rpb, const float* __restrict__ w1,
    const float* __restrict__ b1, const float* __restrict__ w2,
    float* __restrict__ table16) {
  __shared__ float hid[512];
  const int p = blockIdx.x;   // 0..3374
  const int t = threadIdx.x;  // 0..511
  const float r0 = rpb[p * 3 + 0], r1 = rpb[p * 3 + 1], r2 = rpb[p * 3 + 2];
  float hv = fmaf(r0, w1[t * 3 + 0],
             fmaf(r1, w1[t * 3 + 1],
             fmaf(r2, w1[t * 3 + 2], b1[t])));
  hid[t] = fmaxf(hv, 0.0f);
  __syncthreads();
  const int h = t >> 6, lane = t & 63;  // 8 waves, one head per wave
  float s = 0.0f;
#pragma unroll
  for (int u = 0; u < 8; ++u)
    s = fmaf(hid[lane + u * 64], w2[h * 512 + lane + u * 64], s);
#pragma unroll
  for (int off = 32; off > 0; off >>= 1) s += __shfl_down(s, off);
  if (lane == 0) table16[p * 8 + h] = 23.08312065f / (1.0f + __expf(-s));  // 16*log2e*sigmoid
}

// ---------------- kernel 2: combined centered bias+mask (bf16), one-pass ----------------
__global__ __launch_bounds__(256) void cmb_kernel(
    const int* __restrict__ rpb_idx, const float* __restrict__ table16,
    const float* __restrict__ mask, u16* __restrict__ cmb) {
  const int ij0 = (blockIdx.x * 256 + threadIdx.x) * 4;  // 0..262140
  const int w = blockIdx.y;                              // 0..15
  const float4 m4 = *reinterpret_cast<const float4*>(mask + (size_t)w * 262144 + ij0);
  const int4 i4 = *reinterpret_cast<const int4*>(rpb_idx + ij0);
  float ta[8], tb[8], tc[8], td[8];
  *reinterpret_cast<float4*>(&ta[0]) = *reinterpret_cast<const float4*>(table16 + i4.x * 8);
  *reinterpret_cast<float4*>(&ta[4]) = *reinterpret_cast<const float4*>(table16 + i4.x * 8 + 4);
  *reinterpret_cast<float4*>(&tb[0]) = *reinterpret_cast<const float4*>(table16 + i4.y * 8);
  *reinterpret_cast<float4*>(&tb[4]) = *reinterpret_cast<const float4*>(table16 + i4.y * 8 + 4);
  *reinterpret_cast<float4*>(&tc[0]) = *reinterpret_cast<const float4*>(table16 + i4.z * 8);
  *reinterpret_cast<float4*>(&tc[4]) = *reinterpret_cast<const float4*>(table16 + i4.z * 8 + 4);
  *reinterpret_cast<float4*>(&td[0]) = *reinterpret_cast<const float4*>(table16 + i4.w * 8);
  *reinterpret_cast<float4*>(&td[4]) = *reinterpret_cast<const float4*>(table16 + i4.w * 8 + 4);
  const float b0 = m4.x * LOG2E - CMB_SHIFT;
  const float b1 = m4.y * LOG2E - CMB_SHIFT;
  const float b2 = m4.z * LOG2E - CMB_SHIFT;
  const float b3 = m4.w * LOG2E - CMB_SHIFT;
  u16* outp = cmb + (size_t)w * 8 * 262144 + ij0;
#pragma unroll
  for (int h = 0; h < 8; ++h) {
    uint2 o;
    o.x = cvt_pk_bf16(ta[h] + b0, tb[h] + b1);
    o.y = cvt_pk_bf16(tc[h] + b2, td[h] + b3);
    *reinterpret_cast<uint2*>(outp + (size_t)h * 262144) = o;
  }
}

// ---------------- kernel 3: qkv GEMM, bf16 MFMA, prefetched ----------------
__global__ __launch_bounds__(256) void qkv_mfma(
    const float* __restrict__ x, const float* __restrict__ w,
    u16* __restrict__ qbuf, u16* __restrict__ kbuf, u16* __restrict__ vbuf) {
  __shared__ u16 As[128 * 64];
  __shared__ u16 Bs[128 * 64];
  const int tid = threadIdx.x;
  const int flat = blockIdx.x;                  // 0..3071
  const int wrk = (flat & 7) * 384 + (flat >> 3);
  const int bm = wrk / 6;                       // 0..511
  const int bn = wrk - bm * 6;                  // 0..5
  const int m0 = bm * 128, n0 = bn * 128;
  const float scl = (bn < 2) ? QSL : 1.0f;
  const int lane = tid & 63, wid = tid >> 6;
  const int wm = wid >> 1, wn = wid & 1;
  const int lq = lane & 15, g = lane >> 4;
  const f32x4 fz = {0.f, 0.f, 0.f, 0.f};
  f32x4 acc[4][4];
#pragma unroll
  for (int i = 0; i < 4; ++i)
#pragma unroll
    for (int j = 0; j < 4; ++j) acc[i][j] = fz;

  const int r0 = tid >> 3;                      // 0..31
  const int ch = tid & 7;                       // 16B chunk within row
  const int sx = (ch ^ (r0 & 7)) << 3;          // swizzled u16 offset (const: rr*32 keeps row&7)

  float4 ga[4][2], gb[4][2];
  auto gload = [&](int k0) {
#pragma unroll
    for (int rr = 0; rr < 4; ++rr) {
      const int r = r0 + rr * 32;
      const float* ax = x + (size_t)(m0 + r) * 256 + k0 + ch * 8;
      ga[rr][0] = *reinterpret_cast<const float4*>(ax);
      ga[rr][1] = *reinterpret_cast<const float4*>(ax + 4);
      const float* bx = w + (size_t)(n0 + r) * 256 + k0 + ch * 8;
      gb[rr][0] = *reinterpret_cast<const float4*>(bx);
      gb[rr][1] = *reinterpret_cast<const float4*>(bx + 4);
    }
  };

  gload(0);
  for (int k0 = 0; k0 < 256; k0 += 64) {
    __syncthreads();  // prior-iter LDS reads done
#pragma unroll
    for (int rr = 0; rr < 4; ++rr) {
      const int r = r0 + rr * 32;
      uint4 pk;
      pk.x = cvt_pk_bf16(ga[rr][0].x, ga[rr][0].y);
      pk.y = cvt_pk_bf16(ga[rr][0].z, ga[rr][0].w);
      pk.z = cvt_pk_bf16(ga[rr][1].x, ga[rr][1].y);
      pk.w = cvt_pk_bf16(ga[rr][1].z, ga[rr][1].w);
      *reinterpret_cast<uint4*>(&As[r * 64 + sx]) = pk;
      pk.x = cvt_pk_bf16(gb[rr][0].x * scl, gb[rr][0].y * scl);
      pk.y = cvt_pk_bf16(gb[rr][0].z * scl, gb[rr][0].w * scl);
      pk.z = cvt_pk_bf16(gb[rr][1].x * scl, gb[rr][1].y * scl);
      pk.w = cvt_pk_bf16(gb[rr][1].z * scl, gb[rr][1].w * scl);
      *reinterpret_cast<uint4*>(&Bs[r * 64 + sx]) = pk;
    }
    __syncthreads();
    if (k0 + 64 < 256) gload(k0 + 64);  // prefetch next step under compute
#pragma unroll
    for (int ks = 0; ks < 2; ++ks) {
      bf16x8 xf[4], wf[4];
#pragma unroll
      for (int mt = 0; mt < 4; ++mt) {
        const int row = wm * 64 + mt * 16 + lq;
        xf[mt] = *reinterpret_cast<const bf16x8*>(
            &As[row * 64 + (((ks * 4 + g) ^ (row & 7)) << 3)]);
      }
#pragma unroll
      for (int nt = 0; nt < 4; ++nt) {
        const int row = wn * 64 + nt * 16 + lq;
        wf[nt] = *reinterpret_cast<const bf16x8*>(
            &Bs[row * 64 + (((ks * 4 + g) ^ (row & 7)) << 3)]);
      }
#pragma unroll
      for (int mt = 0; mt < 4; ++mt)
#pragma unroll
        for (int nt = 0; nt < 4; ++nt)
          acc[mt][nt] = __builtin_amdgcn_mfma_f32_16x16x32_bf16(
              wf[nt], xf[mt], acc[mt][nt], 0, 0, 0);
    }
  }
  // epilogue: lane holds out[m][n=..+4g+r] (acc[mt][nt][r]), scatter bf16 to (b,h,i,d)
  const int sec = bn >> 1;  // 0=q,1=k,2=v (uniform per block)
  u16* dst = sec == 0 ? qbuf : (sec == 1 ? kbuf : vbuf);
#pragma unroll
  for (int mt = 0; mt < 4; ++mt) {
    const int m = m0 + wm * 64 + mt * 16 + lq;
    const int b = m >> 9, ii = m & 511;
#pragma unroll
    for (int nt = 0; nt < 4; ++nt) {
      const int n = n0 + wn * 64 + nt * 16 + 4 * g;
      const int h = (n & 255) >> 5;
      const int d = n & 31;
      const size_t off = ((size_t)(b * 8 + h) * 512 + ii) * 32 + d;
      uint2 o2;
      o2.x = cvt_pk_bf16(acc[mt][nt][0], acc[mt][nt][1]);
      o2.y = cvt_pk_bf16(acc[mt][nt][2], acc[mt][nt][3]);
      *reinterpret_cast<uint2*>(dst + off) = o2;
    }
  }
}

// ---------------- kernel 4: MFMA attention (R6/R9/R11-proven, FROZEN byte-identical) ----------------
__global__ __launch_bounds__(256, 2) void attn_mfma(
    u16* qbuf,  // in: scaled Q; out: attention output (own rows only)
    const u16* __restrict__ kbuf, const u16* __restrict__ vbuf,
    const u16* __restrict__ cmb) {
  __shared__ u16 Klds[512 * 32];   // row-major keys, XOR-swizzled 16B chunks
  __shared__ u16 Vtlds[32 * 512];  // V transposed [d][n], XOR-swizzled
  const int t = threadIdx.x;
  const int qc = blockIdx.x, h = blockIdx.y;
  const int bz = blockIdx.z;
  const int b = ((bz & 15) << 3) | (bz >> 4);  // co-schedule same (b&15) blocks
  const size_t bh = (size_t)b * 8 + h;
  const u16* kb = kbuf + bh * 16384;
  const u16* vb = vbuf + bh * 16384;

#pragma unroll
  for (int c = 0; c < 8; ++c) {
    const int cid = t + c * 256;
    const int key = cid >> 2, ch = cid & 3;
    const uint4 kd = *reinterpret_cast<const uint4*>(kb + cid * 8);
    const int idx = key * 32 + ((ch * 8) ^ (((key >> 1) & 3) << 3));
    *reinterpret_cast<uint4*>(&Klds[idx]) = kd;
  }
#pragma unroll
  for (int r = 0; r < 2; ++r) {
    const int n = t + r * 256;
    const uint4 v0 = *reinterpret_cast<const uint4*>(vb + n * 32);
    const uint4 v1 = *reinterpret_cast<const uint4*>(vb + n * 32 + 8);
    const uint4 v2 = *reinterpret_cast<const uint4*>(vb + n * 32 + 16);
    const uint4 v3 = *reinterpret_cast<const uint4*>(vb + n * 32 + 24);
    const u32 wv16[16] = {v0.x, v0.y, v0.z, v0.w, v1.x, v1.y, v1.z, v1.w,
                          v2.x, v2.y, v2.z, v2.w, v3.x, v3.y, v3.z, v3.w};
#pragma unroll
    for (int u = 0; u < 16; ++u) {
      const int d0 = 2 * u, d1 = 2 * u + 1;
      Vtlds[d0 * 512 + (n ^ ((d0 & 7) << 3))] = (u16)(wv16[u] & 0xffffu);
      Vtlds[d1 * 512 + (n ^ ((d1 & 7) << 3))] = (u16)(wv16[u] >> 16);
    }
  }
  __syncthreads();

  const int lane = t & 63;
  const int lq = lane & 15, g = lane >> 4;
  const int wv = t >> 6;
  const int q0 = qc * 256 + wv * 64;

  bf16x8 Qf[4];
  u16* qrowbase = qbuf + bh * 16384;
#pragma unroll
  for (int qt = 0; qt < 4; ++qt)
    Qf[qt] = *reinterpret_cast<const bf16x8*>(qrowbase + (q0 + qt * 16 + lq) * 32 + g * 8);

  const u16* cmbp[4];
  const size_t whbase = (size_t)((b & 15) * 8 + h) * 262144;
#pragma unroll
  for (int qt = 0; qt < 4; ++qt)
    cmbp[qt] = cmb + whbase + (size_t)(q0 + qt * 16 + lq) * 512 + 4 * g;

  const f32x4 fzero = {0.f, 0.f, 0.f, 0.f};
  f32x4 o[2][4];
  f32x4 lsum4[4];
#pragma unroll
  for (int qt = 0; qt < 4; ++qt) {
    lsum4[qt] = fzero;
    o[0][qt] = fzero;
    o[1][qt] = fzero;
  }

  for (int j0 = 0; j0 < 512; j0 += 64) {
    bf16x8 Ak[4];
#pragma unroll
    for (int kt = 0; kt < 4; ++kt) {
      const int key = j0 + kt * 16 + lq;
      const int idx = key * 32 + ((g * 8) ^ (((key >> 1) & 3) << 3));
      Ak[kt] = *reinterpret_cast<const bf16x8*>(&Klds[idx]);
    }
    f32x4 s[4][4];
#pragma unroll
    for (int kt = 0; kt < 4; ++kt)
#pragma unroll
      for (int qt = 0; qt < 4; ++qt) {
        const uint2 cc = *reinterpret_cast<const uint2*>(cmbp[qt] + j0 + kt * 16);
        f32x4 ci;
        ci[0] = __uint_as_float((cc.x & 0xffffu) << 16);
        ci[1] = __uint_as_float(cc.x & 0xffff0000u);
        ci[2] = __uint_as_float((cc.y & 0xffffu) << 16);
        ci[3] = __uint_as_float(cc.y & 0xffff0000u);
        s[kt][qt] = __builtin_amdgcn_mfma_f32_16x16x32_bf16(Ak[kt], Qf[qt], ci, 0, 0, 0);
      }
#pragma unroll
    for (int kt = 0; kt < 4; ++kt) {
      bf16x4 Av[2];
#pragma unroll
      for (int dt = 0; dt < 2; ++dt) {
        const int d = dt * 16 + lq;
        const int n0 = j0 + kt * 16 + 4 * g;
        const int idx = d * 512 + (n0 ^ ((d & 7) << 3));
        Av[dt] = *reinterpret_cast<const bf16x4*>(&Vtlds[idx]);
      }
#pragma unroll
      for (int qt = 0; qt < 4; ++qt) {
        f32x4 p = s[kt][qt];
        p[0] = __builtin_amdgcn_exp2f(p[0]);
        p[1] = __builtin_amdgcn_exp2f(p[1]);
        p[2] = __builtin_amdgcn_exp2f(p[2]);
        p[3] = __builtin_amdgcn_exp2f(p[3]);
        lsum4[qt] += p;
        union { u32 u[2]; bf16x4 v; } bp;
        bp.u[0] = cvt_pk_bf16(p[0], p[1]);
        bp.u[1] = cvt_pk_bf16(p[2], p[3]);
        o[0][qt] = __builtin_amdgcn_mfma_f32_16x16x16bf16_1k(Av[0], bp.v, o[0][qt], 0, 0, 0);
        o[1][qt] = __builtin_amdgcn_mfma_f32_16x16x16bf16_1k(Av[1], bp.v, o[1][qt], 0, 0, 0);
      }
    }
  }
#pragma unroll
  for (int qt = 0; qt < 4; ++qt) {
    float l = (lsum4[qt][0] + lsum4[qt][1]) + (lsum4[qt][2] + lsum4[qt][3]);
    l += __shfl_xor(l, 16);
    l += __shfl_xor(l, 32);
    const float inv = 1.0f / l;
    u16* orow = qrowbase + (q0 + qt * 16 + lq) * 32;
#pragma unroll
    for (int dt = 0; dt < 2; ++dt) {
      uint2 w2;
      w2.x = cvt_pk_bf16(o[dt][qt][0] * inv, o[dt][qt][1] * inv);
      w2.y = cvt_pk_bf16(o[dt][qt][2] * inv, o[dt][qt][3] * inv);
      *reinterpret_cast<uint2*>(orow + dt * 16 + 4 * g) = w2;
    }
  }
}

// ---------------- kernel 5: proj GEMM, bf16 MFMA, bn-merged ----------------
// out[m][n] = sum_c attnout[m][c]*proj_w[n][c] + pb[n], M=65536, N=256, K=256.
// One block per 128-row tile computes BOTH 128-col halves: A (scattered
// (b,h,i,d) gather) staged once, two Bs tiles, two acc sets. LDS 48KB.
__global__ __launch_bounds__(256, 2) void proj_mfma(
    const u16* __restrict__ abuf, const float* __restrict__ w,
    const float* __restrict__ pb, float* __restrict__ out) {
  __shared__ u16 As[128 * 64];
  __shared__ u16 Bs0[128 * 64];
  __shared__ u16 Bs1[128 * 64];
  const int tid = threadIdx.x;
  const int bm = blockIdx.x;  // 0..511
  const int m0 = bm * 128;
  const int lane = tid & 63, wid = tid >> 6;
  const int wm = wid >> 1, wn = wid & 1;
  const int lq = lane & 15, g = lane >> 4;
  const f32x4 fz = {0.f, 0.f, 0.f, 0.f};
  f32x4 acc0[4][4], acc1[4][4];
#pragma unroll
  for (int i = 0; i < 4; ++i)
#pragma unroll
    for (int j = 0; j < 4; ++j) { acc0[i][j] = fz; acc1[i][j] = fz; }

  const int r0 = tid >> 3;
  const int ch = tid & 7;
  const int sx = (ch ^ (r0 & 7)) << 3;
  // A row -> (b, i) decomposition (b uniform per block since 128 | 512)
  const int ab = m0 >> 9;
  const u16* abase = abuf + (size_t)ab * 8 * 16384;
  const int dA0 = (ch & 3) * 8;

  for (int k0 = 0; k0 < 256; k0 += 64) {
    const int hA0 = (k0 >> 5) + (ch >> 2);
    __syncthreads();  // prior-iter LDS reads done
#pragma unroll
    for (int rr = 0; rr < 4; ++rr) {
      const int r = r0 + rr * 32;
      const uint4 ga = *reinterpret_cast<const uint4*>(
          abase + ((size_t)hA0 * 512 + ((m0 & 511) + r)) * 32 + dA0);
      const float* bx0 = w + (size_t)r * 256 + k0 + ch * 8;          // n rows 0..127
      const float* bx1 = w + (size_t)(128 + r) * 256 + k0 + ch * 8;  // n rows 128..255
      const float4 b00 = *reinterpret_cast<const float4*>(bx0);
      const float4 b01 = *reinterpret_cast<const float4*>(bx0 + 4);
      const float4 b10 = *reinterpret_cast<const float4*>(bx1);
      const float4 b11 = *reinterpret_cast<const float4*>(bx1 + 4);
      *reinterpret_cast<uint4*>(&As[r * 64 + sx]) = ga;
      uint4 pk;
      pk.x = cvt_pk_bf16(b00.x, b00.y); pk.y = cvt_pk_bf16(b00.z, b00.w);
      pk.z = cvt_pk_bf16(b01.x, b01.y); pk.w = cvt_pk_bf16(b01.z, b01.w);
      *reinterpret_cast<uint4*>(&Bs0[r * 64 + sx]) = pk;
      pk.x = cvt_pk_bf16(b10.x, b10.y); pk.y = cvt_pk_bf16(b10.z, b10.w);
      pk.z = cvt_pk_bf16(b11.x, b11.y); pk.w = cvt_pk_bf16(b11.z, b11.w);
      *reinterpret_cast<uint4*>(&Bs1[r * 64 + sx]) = pk;
    }
    __syncthreads();
#pragma unroll
    for (int ks = 0; ks < 2; ++ks) {
      bf16x8 xf[4];
#pragma unroll
      for (int mt = 0; mt < 4; ++mt) {
        const int row = wm * 64 + mt * 16 + lq;
        xf[mt] = *reinterpret_cast<const bf16x8*>(
            &As[row * 64 + (((ks * 4 + g) ^ (row & 7)) << 3)]);
      }
#pragma unroll
      for (int nt = 0; nt < 4; ++nt) {
        const int row = wn * 64 + nt * 16 + lq;
        const int off = row * 64 + (((ks * 4 + g) ^ (row & 7)) << 3);
        const bf16x8 wf0 = *reinterpret_cast<const bf16x8*>(&Bs0[off]);
        const bf16x8 wf1 = *reinterpret_cast<const bf16x8*>(&Bs1[off]);
#pragma unroll
        for (int mt = 0; mt < 4; ++mt) {
          acc0[mt][nt] = __builtin_amdgcn_mfma_f32_16x16x32_bf16(
              wf0, xf[mt], acc0[mt][nt], 0, 0, 0);
          acc1[mt][nt] = __builtin_amdgcn_mfma_f32_16x16x32_bf16(
              wf1, xf[mt], acc1[mt][nt], 0, 0, 0);
        }
      }
    }
  }
  // epilogue: f32 out, row-major, +bias (both 128-col halves)
#pragma unroll
  for (int mt = 0; mt < 4; ++mt) {
    const int m = m0 + wm * 64 + mt * 16 + lq;
#pragma unroll
    for (int nt = 0; nt < 4; ++nt) {
      const int n = wn * 64 + nt * 16 + 4 * g;
      const float4 pb0 = *reinterpret_cast<const float4*>(pb + n);
      *reinterpret_cast<float4*>(out + (size_t)m * 256 + n) =
          make_float4(acc0[mt][nt][0] + pb0.x, acc0[mt][nt][1] + pb0.y,
                      acc0[mt][nt][2] + pb0.z, acc0[mt][nt][3] + pb0.w);
      const float4 pb1 = *reinterpret_cast<const float4*>(pb + 128 + n);
      *reinterpret_cast<float4*>(out + (size_t)m * 256 + 128 + n) =
          make_float4(acc1[mt][nt][0] + pb1.x, acc1[mt][nt][1] + pb1.y,
                      acc1[mt][nt][2] + pb1.z, acc1[mt][nt][3] + pb1.w);
    }
  }
}

extern "C" void kernel_launch(void* const* d_in, const int* in_sizes, int n_in,
                              void* d_out, int out_size, void* d_ws, size_t ws_size,
                              hipStream_t stream) {
  const float* x = (const float*)d_in[0];
  const float* mask = (const float*)d_in[1];
  const float* qkv_w = (const float*)d_in[2];
  const float* proj_w = (const float*)d_in[3];
  const float* proj_b = (const float*)d_in[4];
  const float* cpb_w1 = (const float*)d_in[5];
  const float* cpb_b1 = (const float*)d_in[6];
  const float* cpb_w2 = (const float*)d_in[7];
  const float* rpb = (const float*)d_in[8];
  const int* rpb_idx = (const int*)d_in[9];
  float* out = (float*)d_out;

  char* ws = (char*)d_ws;
  u16* qbuf = (u16*)(ws);                       // 33,554,432 B
  u16* kbuf = (u16*)(ws + 33554432);            // 33,554,432 B
  u16* vbuf = (u16*)(ws + 67108864);            // 33,554,432 B
  u16* cmb = (u16*)(ws + 100663296);            // 67,108,864 B
  float* table16 = (float*)(ws + 167772160);    //    108,000 B

  cpb_kernel<<<3375, 512, 0, stream>>>(rpb, cpb_w1, cpb_b1, cpb_w2, table16);
  cmb_kernel<<<dim3(256, 16), 256, 0, stream>>>(rpb_idx, table16, mask, cmb);
  qkv_mfma<<<3072, 256, 0, stream>>>(x, qkv_w, qbuf, kbuf, vbuf);
  attn_mfma<<<dim3(2, 8, 128), 256, 0, stream>>>(qbuf, kbuf, vbuf, cmb);
  proj_mfma<<<512, 256, 0, stream>>>(qbuf, proj_w, proj_b, out);
}